// Round 11
// baseline (911.298 us; speedup 1.0000x reference)
//
#include <hip/hip_runtime.h>
#include <hip/hip_bf16.h>
#include <math.h>

typedef __hip_bfloat16 bf16;
typedef __bf16 bf16x8 __attribute__((ext_vector_type(8)));
typedef float f32x4 __attribute__((ext_vector_type(4)));

#define NDEPTH 4
#define DIM 768
#define HEADS 12
#define DH 64
#define INNER 768
#define FFI 2048
#define BB 4
#define NN 1024
#define ROWS (BB*NN)   // 4096

__device__ __forceinline__ void async_cp16(const bf16* g, bf16* l) {
  __builtin_amdgcn_global_load_lds(
      (const __attribute__((address_space(1))) unsigned int*)g,
      (__attribute__((address_space(3))) unsigned int*)l, 16, 0, 0);
}

// ---------------------------------------------------------------------------
// bf16 MFMA GEMM body (R1 config — measured best for the N<=1536 GEMMs).
// C[MxN] = A[MxK] @ Bt[NxK]^T. 128xBN tile, BK=64, 4 waves, XOR-swizzled LDS
// (0 bank conflicts measured). 2-phase double-buffered pipeline: stage next
// K-tile before computing current; one __syncthreads per step.
// GEMM-plateau history: depth-2/3-buffer (R2), 1D XCD swizzle (R3), BK=32
// (R4), 256^2 2ph (R5 neutral), 8-phase counted-vmcnt (R7/R8 null after
// conflict fix), fused non-split K=2048 (R9 anomaly, build-tied — confirmed
// by R10 restore). ~500 TF is this small-K regime's measured plateau.
// ---------------------------------------------------------------------------
template<int BN, bool GELU, bool VOUT, int K, int LD>
__device__ __forceinline__ void gemm_body(
    const bf16* __restrict__ A, const bf16* __restrict__ Bt,
    bf16* __restrict__ Cb, float* __restrict__ Cf, const float* __restrict__ Rf,
    bf16* __restrict__ Vt, int M, int N, int bx, int by, bf16* As, bf16* Bs)
{
  constexpr int WN = BN / 2;      // wave col extent
  constexpr int NT = WN / 16;     // col MFMA tiles per wave
  const int tid  = threadIdx.x;
  const int lane = tid & 63, w = tid >> 6;
  const int quad = lane >> 4, l16 = lane & 15;
  const int wr = w >> 1, wc = w & 1;
  const int m0 = by * 128, n0 = bx * BN;

  f32x4 acc[4][NT] = {};

  constexpr int CHA = 128 * 8;    // A chunks (8 x 16B per 64-elem row)
  constexpr int CH  = CHA + BN * 8;
  constexpr int NCH = CH / 256;   // chunks per thread
  constexpr int NTK = K / 64;     // K-steps

  auto stage = [&](int kk, int buf) {
    bf16* Asb = As + buf * (128*64);
    bf16* Bsb = Bs + buf * (BN*64);
    #pragma unroll
    for (int t = 0; t < NCH; ++t) {
      int c0 = w*64 + t*256;      // wave-uniform LDS base chunk
      int ch = c0 + lane;
      if (c0 < CHA) {
        int r = ch >> 3, j = (ch & 7) ^ (r & 7);
        async_cp16(&A[(size_t)(m0 + r)*LD + kk + j*8], &Asb[(size_t)c0*8]);
      } else {
        int ch2 = ch - CHA, r = ch2 >> 3, j = (ch2 & 7) ^ (r & 7);
        async_cp16(&Bt[(size_t)(n0 + r)*LD + kk + j*8], &Bsb[(size_t)(c0 - CHA)*8]);
      }
    }
  };

  stage(0, 0);
  __syncthreads();   // vmcnt(0) drain + barrier

  #pragma unroll
  for (int t = 0; t < NTK; ++t) {
    const int buf = t & 1;
    if (t + 1 < NTK) stage((t + 1) * 64, buf ^ 1);

    const bf16* Asb = As + buf * (128*64);
    const bf16* Bsb = Bs + buf * (BN*64);

    #pragma unroll
    for (int kc = 0; kc < 2; ++kc) {
      bf16x8 bfr[NT];
      #pragma unroll
      for (int nt = 0; nt < NT; ++nt) {
        int rb = wc*WN + nt*16 + l16;
        int c  = (kc*4 + quad) ^ (rb & 7);
        bfr[nt] = *(const bf16x8*)&Bsb[rb*64 + c*8];
      }
      #pragma unroll
      for (int mt = 0; mt < 4; ++mt) {
        int ra = wr*64 + mt*16 + l16;
        int ca = (kc*4 + quad) ^ (ra & 7);
        bf16x8 af = *(const bf16x8*)&Asb[ra*64 + ca*8];
        #pragma unroll
        for (int nt = 0; nt < NT; ++nt)
          acc[mt][nt] = __builtin_amdgcn_mfma_f32_16x16x32_bf16(af, bfr[nt], acc[mt][nt], 0, 0, 0);
      }
    }
    if (t + 1 < NTK) __syncthreads();
  }

  #pragma unroll
  for (int mt = 0; mt < 4; ++mt) {
    #pragma unroll
    for (int nt = 0; nt < NT; ++nt) {
      int row = m0 + wr*64 + mt*16 + quad*4;
      int col = n0 + wc*WN + nt*16 + l16;
      if (GELU) {
        #pragma unroll
        for (int r = 0; r < 4; ++r) {
          float v = acc[mt][nt][r];
          float g = __shfl_xor(v, 1);            // even lane: v=a, g from odd
          if (!(lane & 1)) {
            float ge = 0.5f * g * (1.f + erff(g * 0.70710678118654752f));
            Cb[(size_t)(row + r)*(N >> 1) + (col >> 1)] = __float2bfloat16(v * ge);
          }
        }
      } else if (VOUT) {
        if (col < INNER) {                       // K half (wave-uniform branch)
          #pragma unroll
          for (int r = 0; r < 4; ++r)
            Cb[(size_t)(row + r)*INNER + col] = __float2bfloat16(acc[mt][nt][r]);
        } else {                                 // V half -> (b,h,dh,n) packed
          int c2 = col - INNER, hh = c2 >> 6, d = c2 & 63;
          int b = row >> 10, nn = row & 1023;
          union { ushort4 u4; bf16 h4[4]; } p;
          #pragma unroll
          for (int r = 0; r < 4; ++r) p.h4[r] = __float2bfloat16(acc[mt][nt][r]);
          *(ushort4*)&Vt[(((size_t)b*HEADS + hh)*DH + d)*NN + nn] = p.u4;
        }
      } else {
        #pragma unroll
        for (int r = 0; r < 4; ++r) {
          float v = acc[mt][nt][r];
          size_t idx = (size_t)(row + r) * N + col;
          if (Rf) v += Rf[idx];
          if (Cf) Cf[idx] = v;
          if (Cb) Cb[idx] = __float2bfloat16(v);
        }
      }
    }
  }
}

// Split-K=2: z selects K-half; partials to P[z*M*N]
template<int BN, int KH, int LD>
__global__ __launch_bounds__(256) void gemm_splitk_kernel(
    const bf16* __restrict__ A, const bf16* __restrict__ Bt,
    float* __restrict__ P, int M, int N)
{
  __shared__ __align__(16) bf16 As[2*128*64];
  __shared__ __align__(16) bf16 Bs[2*BN*64];
  const int z = blockIdx.z;
  gemm_body<BN,false,false,KH,LD>(A + (size_t)z*KH, Bt + (size_t)z*KH, nullptr,
                                  P + (size_t)z*M*N, nullptr, nullptr,
                                  M, N, blockIdx.x, blockIdx.y, As, Bs);
}

// q = h @ wq (BN=64); kv = x @ wkv (BN=128, k compact + v transposed) fused
__global__ __launch_bounds__(256) void qkv_kernel(
    const bf16* __restrict__ h, const bf16* __restrict__ x16,
    const bf16* __restrict__ wqT, const bf16* __restrict__ wkvT,
    bf16* __restrict__ qb, bf16* __restrict__ kb, bf16* __restrict__ vt)
{
  __shared__ __align__(16) bf16 As[2*128*64];
  __shared__ __align__(16) bf16 Bs[2*128*64];
  if (blockIdx.z == 0)
    gemm_body<64,false,false,768,768>(h, wqT, qb, nullptr, nullptr, nullptr,
                                      ROWS, INNER, blockIdx.x, blockIdx.y, As, Bs);
  else
    gemm_body<128,false,true,768,768>(x16, wkvT, kb, nullptr, nullptr, vt,
                                      ROWS, 2*INNER, blockIdx.x, blockIdx.y, As, Bs);
}

// ---------------------------------------------------------------------------
// 256x256 8-wave GEMM + GELU for FF1 (M=N=4096, K=768). R6 2-PHASE form
// (measured 50.0us — best). 2D-region XCD swizzle kept (FETCH 28->19MB).
// ---------------------------------------------------------------------------
__global__ __launch_bounds__(512) void gemm256_kernel(
    const bf16* __restrict__ A, const bf16* __restrict__ Bt,
    bf16* __restrict__ Cb, int M, int N)
{
  __shared__ __align__(16) bf16 As[2][256*64];
  __shared__ __align__(16) bf16 Bs[2][256*64];

  const int tid  = threadIdx.x;
  const int lane = tid & 63, wv = tid >> 6;
  const int quad = lane >> 4, l16 = lane & 15;
  const int wr = wv >> 2, wc = wv & 3;          // 2 x 4 wave grid

  // 2D-region XCD swizzle (bijective for the 16x16 grid)
  const int lin = blockIdx.y * gridDim.x + blockIdx.x;
  const int xcd = lin & 7, loc = lin >> 3;
  const int bxs = (xcd & 1) * 8 + (loc & 7);
  const int bys = (xcd >> 1) * 4 + (loc >> 3);
  const int m0 = bys * 256, n0 = bxs * 256;

  f32x4 acc[8][4] = {};

  auto stage = [&](int kk, int buf) {
    #pragma unroll
    for (int t = 0; t < 8; ++t) {
      int c0 = wv*64 + t*512;                   // wave-uniform base chunk
      int ch = c0 + lane;
      if (c0 < 2048) {
        int r = ch >> 3, j = (ch & 7) ^ (r & 7);
        async_cp16(&A[(size_t)(m0 + r)*768 + kk + j*8], &As[buf][(size_t)c0*8]);
      } else {
        int ch2 = ch - 2048, r = ch2 >> 3, j = (ch2 & 7) ^ (r & 7);
        async_cp16(&Bt[(size_t)(n0 + r)*768 + kk + j*8], &Bs[buf][(size_t)(c0 - 2048)*8]);
      }
    }
  };

  stage(0, 0);
  __syncthreads();

  #pragma unroll
  for (int t = 0; t < 12; ++t) {                // K = 768 = 12 x 64
    const int buf = t & 1;
    if (t + 1 < 12) stage((t + 1) * 64, buf ^ 1);

    const bf16* Asb = &As[buf][0];
    const bf16* Bsb = &Bs[buf][0];

    #pragma unroll
    for (int kc = 0; kc < 2; ++kc) {
      bf16x8 bfr[4];
      #pragma unroll
      for (int nt = 0; nt < 4; ++nt) {
        int rb = wc*64 + nt*16 + l16;
        int c  = (kc*4 + quad) ^ (rb & 7);
        bfr[nt] = *(const bf16x8*)&Bsb[rb*64 + c*8];
      }
      #pragma unroll
      for (int mt = 0; mt < 8; ++mt) {
        int ra = wr*128 + mt*16 + l16;
        int ca = (kc*4 + quad) ^ (ra & 7);
        bf16x8 af = *(const bf16x8*)&Asb[ra*64 + ca*8];
        #pragma unroll
        for (int nt = 0; nt < 4; ++nt)
          acc[mt][nt] = __builtin_amdgcn_mfma_f32_16x16x32_bf16(af, bfr[nt], acc[mt][nt], 0, 0, 0);
      }
    }
    if (t + 1 < 12) __syncthreads();
  }

  // GELU epilogue: cols interleave (a,g); even lane holds a, odd holds g
  #pragma unroll
  for (int mt = 0; mt < 8; ++mt) {
    #pragma unroll
    for (int nt = 0; nt < 4; ++nt) {
      int row = m0 + wr*128 + mt*16 + quad*4;
      int col = n0 + wc*64 + nt*16 + l16;
      #pragma unroll
      for (int r = 0; r < 4; ++r) {
        float v = acc[mt][nt][r];
        float g = __shfl_xor(v, 1);
        if (!(lane & 1)) {
          float ge = 0.5f * g * (1.f + erff(g * 0.70710678118654752f));
          Cb[(size_t)(row + r)*(N >> 1) + (col >> 1)] = __float2bfloat16(v * ge);
        }
      }
    }
  }
}

// ---------------------------------------------------------------------------
// LayerNorm (row = 768, f32 in, bf16 out) — used once for layer-0 attn-LN
// ---------------------------------------------------------------------------
__global__ __launch_bounds__(256) void ln_kernel(
    const float* __restrict__ x, const float* __restrict__ g,
    const float* __restrict__ bta, bf16* __restrict__ out)
{
  const int row = blockIdx.x, tid = threadIdx.x;
  const size_t base = (size_t)row * DIM;
  float v[3];
  #pragma unroll
  for (int j = 0; j < 3; ++j) v[j] = x[base + tid + j*256];
  float s  = v[0] + v[1] + v[2];
  float ss = v[0]*v[0] + v[1]*v[1] + v[2]*v[2];
  #pragma unroll
  for (int off = 32; off; off >>= 1) { s += __shfl_xor(s, off); ss += __shfl_xor(ss, off); }
  __shared__ float red[8];
  int w = tid >> 6;
  if ((tid & 63) == 0) { red[w] = s; red[w + 4] = ss; }
  __syncthreads();
  s  = red[0] + red[1] + red[2] + red[3];
  ss = red[4] + red[5] + red[6] + red[7];
  float mean = s * (1.f/768.f);
  float var  = ss * (1.f/768.f) - mean*mean;
  float rstd = rsqrtf(fmaxf(var, 0.f) + 1e-5f);
  #pragma unroll
  for (int j = 0; j < 3; ++j) {
    int c = tid + j*256;
    float bv = bta ? bta[c] : 0.f;
    out[base + c] = __float2bfloat16((v[j] - mean) * rstd * g[c] + bv);
  }
}

// ---------------------------------------------------------------------------
// Split-K reduce + residual + optional LN (fused). Row = 768.
// ---------------------------------------------------------------------------
__global__ __launch_bounds__(256) void redln_kernel(
    const float* __restrict__ P0, const float* __restrict__ P1,
    const float* __restrict__ res,
    float* __restrict__ xo32, bf16* __restrict__ xo16, float* __restrict__ outf,
    const float* __restrict__ g, const float* __restrict__ bta,
    bf16* __restrict__ lnout)
{
  const int row = blockIdx.x, tid = threadIdx.x;
  const size_t base = (size_t)row * DIM;
  float v[3];
  #pragma unroll
  for (int j = 0; j < 3; ++j) {
    size_t idx = base + tid + j*256;
    v[j] = res[idx] + P0[idx] + P1[idx];
    if (xo32) xo32[idx] = v[j];
    if (xo16) xo16[idx] = __float2bfloat16(v[j]);
    if (outf) outf[idx] = v[j];
  }
  if (!g) return;
  float s  = v[0] + v[1] + v[2];
  float ss = v[0]*v[0] + v[1]*v[1] + v[2]*v[2];
  #pragma unroll
  for (int off = 32; off; off >>= 1) { s += __shfl_xor(s, off); ss += __shfl_xor(ss, off); }
  __shared__ float red[8];
  int w = tid >> 6;
  if ((tid & 63) == 0) { red[w] = s; red[w + 4] = ss; }
  __syncthreads();
  s  = red[0] + red[1] + red[2] + red[3];
  ss = red[4] + red[5] + red[6] + red[7];
  float mean = s * (1.f/768.f);
  float var  = ss * (1.f/768.f) - mean*mean;
  float rstd = rsqrtf(fmaxf(var, 0.f) + 1e-5f);
  #pragma unroll
  for (int j = 0; j < 3; ++j) {
    int c = tid + j*256;
    float bv = bta ? bta[c] : 0.f;
    lnout[base + c] = __float2bfloat16((v[j] - mean) * rstd * g[c] + bv);
  }
}

// ---------------------------------------------------------------------------
// RoPE (2D, H=32) + L2-norm + per-dim scale; q gets ATTN_SCALE folded in.
// Pair-per-lane; block = 384 threads (12 heads x 32 pairs). -> (b,h,n,dh)
// ---------------------------------------------------------------------------
__global__ __launch_bounds__(384) void rope_kernel(
    const bf16* __restrict__ q, const bf16* __restrict__ kb,
    const float* __restrict__ qsc, const float* __restrict__ ksc,
    bf16* __restrict__ qh, bf16* __restrict__ kh)
{
  const int bn = blockIdx.x;
  const int b = bn >> 10, n = bn & 1023;
  const int tid = threadIdx.x;
  const int h = tid >> 5, pr = tid & 31, d0 = pr*2;
  const float xp = (float)(n & 31), yp = (float)(n >> 5);
  const int t = pr >> 1;
  const float freq = powf(10000.f, -(float)t / 16.f);
  const float ang = (pr & 1) ? yp * freq : xp * freq;
  float sn, cs;
  sincosf(ang, &sn, &cs);
  const float2 qs2 = *(const float2*)&qsc[d0];
  const float2 ks2 = *(const float2*)&ksc[d0];

  union { unsigned int u; bf16 h2[2]; } qa, ka, qo, ko;
  qa.u = *(const unsigned int*)&q [(size_t)bn*INNER + h*64 + d0];
  ka.u = *(const unsigned int*)&kb[(size_t)bn*INNER + h*64 + d0];
  float qre = __bfloat162float(qa.h2[0]), qim = __bfloat162float(qa.h2[1]);
  float kre = __bfloat162float(ka.h2[0]), kim = __bfloat162float(ka.h2[1]);
  float qr = qre*cs - qim*sn, qi = qre*sn + qim*cs;
  float kr = kre*cs - kim*sn, ki = kre*sn + kim*cs;
  float q2 = qr*qr + qi*qi, k2 = kr*kr + ki*ki;
  #pragma unroll
  for (int off = 1; off < 32; off <<= 1) { q2 += __shfl_xor(q2, off); k2 += __shfl_xor(k2, off); }
  float qinv = 8.f / fmaxf(sqrtf(q2), 1e-12f);   // ATTN_SCALE folded into q
  float kinv = 1.f / fmaxf(sqrtf(k2), 1e-12f);
  qo.h2[0] = __float2bfloat16(qr * qinv * qs2.x);
  qo.h2[1] = __float2bfloat16(qi * qinv * qs2.y);
  ko.h2[0] = __float2bfloat16(kr * kinv * ks2.x);
  ko.h2[1] = __float2bfloat16(ki * kinv * ks2.y);
  size_t oi = (((size_t)b*HEADS + h)*NN + n)*DH + d0;
  *(unsigned int*)&qh[oi] = qo.u;
  *(unsigned int*)&kh[oi] = ko.u;
}

// ---------------------------------------------------------------------------
// Flash attention, fixed softmax max (Cauchy-Schwarz bound; 8 folded into q).
// R11: QBLK 64->128 via 8 WAVES (512 thr) — per-wave code UNCHANGED (each
// wave still owns 16 q-rows); only staging counts, Ps[8], grid, offsets
// change. Halves K/V re-reads (8 qt-blocks/head instead of 16) and doubles
// MFMA per staged byte. LDS 67KB -> 2 blocks/CU = 4 waves/SIMD (was 3).
// + XCD co-location: all 8 qt-blocks of one (b,h) map to the SAME XCD
// (lin%8 round-robin assumption): 6 heads x 256KB K/V = 1.5MB per XCD L2 —
// converts cross-XCD L3 hits into L2 hits. Bijective remap.
// R6 async global_load_lds double-buffer + R10 setprio kept.
// ---------------------------------------------------------------------------
__global__ __launch_bounds__(512) void attn_kernel(
    const bf16* __restrict__ qh, const bf16* __restrict__ kh,
    const bf16* __restrict__ vt, const float* __restrict__ qsc,
    const float* __restrict__ ksc, bf16* __restrict__ ob)
{
  __shared__ __align__(16) bf16 Qs[128*64];
  __shared__ __align__(16) bf16 Ks[2][64*64];
  __shared__ __align__(16) bf16 Vs[2][64*64];
  __shared__ __align__(16) bf16 Ps[8][16*72];

  const int tid = threadIdx.x;
  const int lane = tid & 63, w = tid >> 6;      // w in 0..7
  const int quad = lane >> 4, l16 = lane & 15;

  // XCD co-location: lin -> (xcd, j); bh = xcd*6 + j/8, qt = j%8.
  // All 8 qt of a bh have lin = xcd (mod 8) -> same XCD under %8 round-robin.
  const int lin = blockIdx.y * gridDim.x + blockIdx.x;   // 0..383
  const int xg = lin & 7, jj = lin >> 3;                 // jj 0..47
  const int bh = xg * 6 + (jj >> 3);
  const int qt = jj & 7;
  const int b = bh / HEADS, h = bh % HEADS;
  const size_t base = (size_t)bh * NN * DH;

  float mq = fabsf(qsc[lane]), mk = fabsf(ksc[lane]);
  #pragma unroll
  for (int off = 1; off < 64; off <<= 1) {
    mq = fmaxf(mq, __shfl_xor(mq, off));
    mk = fmaxf(mk, __shfl_xor(mk, off));
  }
  const float Mb = 8.f * mq * mk;

  // stage Q once: 128 rows x 64 cols = 1024 chunks, 2/thread,
  // pre-swizzled source -> linear dest
  #pragma unroll
  for (int t = 0; t < 2; ++t) {
    int c0 = w*64 + t*512, ch = c0 + lane;
    int r = ch >> 3, jl = (ch & 7) ^ (r & 7);
    async_cp16(&qh[base + (size_t)(qt*128 + r)*64 + jl*8], &Qs[(size_t)c0*8]);
  }

  // stage one K/V tile (1024 chunks, 2/thread) into buffer buf
  auto stage_kv = [&](int kt0, int buf) {
    #pragma unroll
    for (int t = 0; t < 2; ++t) {
      int c0 = w*64 + t*512, ch = c0 + lane;
      if (c0 < 512) {            // K: rows = n, cols = dh
        int r = ch >> 3, jl = (ch & 7) ^ (r & 7);
        async_cp16(&kh[base + (size_t)(kt0*64 + r)*64 + jl*8],
                   &Ks[buf][(size_t)c0*8]);
      } else {                   // V: rows = dh, cols = n (vt is (b,h,dh,n))
        int ch2 = ch - 512, r = ch2 >> 3, jl = (ch2 & 7) ^ (r & 7);
        async_cp16(&vt[base + (size_t)r*NN + kt0*64 + jl*8],
                   &Vs[buf][(size_t)(c0 - 512)*8]);
      }
    }
  };

  f32x4 o[4] = {};
  float pl[4] = {0.f, 0.f, 0.f, 0.f};

  stage_kv(0, 0);
  __syncthreads();               // drains Q + tile-0 loads

  for (int kt0 = 0; kt0 < NN/64; ++kt0) {
    const int buf = kt0 & 1;
    if (kt0 + 1 < NN/64) stage_kv(kt0 + 1, buf ^ 1);  // async, hides under MFMA

    f32x4 s[4] = {};
    bf16x8 aq[2];
    const int rq = w*16 + l16;   // 0..127: wave w owns Q rows w*16..w*16+15
    #pragma unroll
    for (int kc = 0; kc < 2; ++kc)
      aq[kc] = *(const bf16x8*)&Qs[rq*64 + ((kc*4 + quad) ^ (rq & 7))*8];
    __builtin_amdgcn_s_setprio(1);
    #pragma unroll
    for (int kt = 0; kt < 4; ++kt)
      #pragma unroll
      for (int kc = 0; kc < 2; ++kc) {
        int rb = kt*16 + l16;
        bf16x8 bk = *(const bf16x8*)&Ks[buf][rb*64 + ((kc*4 + quad) ^ (rb & 7))*8];
        s[kt] = __builtin_amdgcn_mfma_f32_16x16x32_bf16(aq[kc], bk, s[kt], 0, 0, 0);
      }
    __builtin_amdgcn_s_setprio(0);

    #pragma unroll
    for (int r = 0; r < 4; ++r) {
      #pragma unroll
      for (int kt = 0; kt < 4; ++kt) {
        float pv = __expf(s[kt][r] - Mb);
        pl[r] += pv;
        Ps[w][(quad*4 + r)*72 + kt*16 + l16] = __float2bfloat16(pv);
      }
    }
    // no barrier: Ps[w] is produced and consumed by the same wave.

    __builtin_amdgcn_s_setprio(1);
    #pragma unroll
    for (int kc = 0; kc < 2; ++kc) {
      bf16x8 ap = *(const bf16x8*)&Ps[w][l16*72 + kc*32 + quad*8];
      #pragma unroll
      for (int nt = 0; nt < 4; ++nt) {
        int rv = nt*16 + l16;
        bf16x8 bv = *(const bf16x8*)&Vs[buf][rv*64 + ((kc*4 + quad) ^ (rv & 7))*8];
        o[nt] = __builtin_amdgcn_mfma_f32_16x16x32_bf16(ap, bv, o[nt], 0, 0, 0);
      }
    }
    __builtin_amdgcn_s_setprio(0);

    if (kt0 + 1 < NN/64) __syncthreads();
  }

  float l[4];
  #pragma unroll
  for (int r = 0; r < 4; ++r) {
    float rs = pl[r];
    #pragma unroll
    for (int off = 1; off < 16; off <<= 1) rs += __shfl_xor(rs, off);
    l[r] = rs;
  }

  #pragma unroll
  for (int nt = 0; nt < 4; ++nt)
    #pragma unroll
    for (int r = 0; r < 4; ++r) {
      int n = qt*128 + w*16 + quad*4 + r;
      int dcol = nt*16 + l16;
      ob[((size_t)(b*NN + n)*HEADS + h)*DH + dcol] = __float2bfloat16(o[nt][r] / l[r]);
    }
}

// ---------------------------------------------------------------------------
// f32 -> bf16 cast (vectorized x8)
// ---------------------------------------------------------------------------
__global__ __launch_bounds__(256) void cast_kernel(
    const float* __restrict__ x, bf16* __restrict__ o)
{
  size_t i = ((size_t)blockIdx.x*256 + threadIdx.x) * 8;
  float4 f0 = *(const float4*)(x + i);
  float4 f1 = *(const float4*)(x + i + 4);
  union { uint4 u; bf16 h[8]; } p;
  p.h[0] = __float2bfloat16(f0.x); p.h[1] = __float2bfloat16(f0.y);
  p.h[2] = __float2bfloat16(f0.z); p.h[3] = __float2bfloat16(f0.w);
  p.h[4] = __float2bfloat16(f1.x); p.h[5] = __float2bfloat16(f1.y);
  p.h[6] = __float2bfloat16(f1.z); p.h[7] = __float2bfloat16(f1.w);
  *(uint4*)(o + i) = p.u;
}

// ---------------------------------------------------------------------------
// Fused weight transpose: 5 weights f32 (RxC) -> bf16 (CxR), one dispatch.
// perm=1 (wff1): output rows interleave a/g columns.
// ---------------------------------------------------------------------------
struct TD { const float* src; bf16* dst; int R, C, base, perm; };
struct TDs5 { TD d[5]; };

__global__ __launch_bounds__(256) void wtrans_kernel(TDs5 a)
{
  const int blk = blockIdx.x;
  int di = 0;
  #pragma unroll
  for (int k = 1; k < 5; ++k) if (blk >= a.d[k].base) di = k;
  const TD d = a.d[di];
  const int local = blk - d.base;
  const int tilesX = d.C >> 5;
  const int by = local / tilesX, bx = local - by*tilesX;
  __shared__ float t[32][33];
  const int tx = threadIdx.x & 31, ty = threadIdx.x >> 5;
  const int c0 = bx*32, r0 = by*32;
  #pragma unroll
  for (int i = 0; i < 4; ++i)
    t[ty + i*8][tx] = d.src[(size_t)(r0 + ty + i*8)*d.C + c0 + tx];
  __syncthreads();
  const int half = d.C >> 1;
  #pragma unroll
  for (int i = 0; i < 4; ++i) {
    int c = c0 + ty + i*8;
    int rout = d.perm ? ((c < half) ? 2*c : 2*(c - half) + 1) : c;
    d.dst[(size_t)rout*d.R + r0 + tx] = __float2bfloat16(t[tx][ty + i*8]);
  }
}

// ---------------------------------------------------------------------------
extern "C" void kernel_launch(void* const* d_in, const int* in_sizes, int n_in,
                              void* d_out, int out_size, void* d_ws, size_t ws_size,
                              hipStream_t stream)
{
  const float* x_in       = (const float*)d_in[0];
  const float* attn_gamma = (const float*)d_in[1];
  const float* wq         = (const float*)d_in[2];
  const float* wkv        = (const float*)d_in[3];
  const float* q_scale    = (const float*)d_in[4];
  const float* k_scale    = (const float*)d_in[5];
  const float* wo         = (const float*)d_in[6];
  const float* ff_gamma   = (const float*)d_in[7];
  const float* ff_beta    = (const float*)d_in[8];
  const float* wff1       = (const float*)d_in[9];
  const float* wff2       = (const float*)d_in[10];
  float* outp = (float*)d_out;
  char* ws = (char*)d_ws;

  const size_t E = (size_t)ROWS * DIM;      // 3,145,728 elems
  float* xw32 = (float*)ws;                     // [0, 12.58M) f32 residual
  bf16*  xw16 = (bf16*)(ws + 12582912);         // bf16 shadow (kv input)
  bf16*  S_h  = (bf16*)(ws + 18874368);         // LN out / attn out
  char*  BIGb = ws + 25165824;                  // 37.75M scratch
  bf16*  WT   = (bf16*)(ws + 62914560);         // transposed weights
  bf16*  qbuf  = (bf16*)BIGb;                   // E elems
  bf16*  kbuf  = qbuf + E;                      // E
  bf16*  qhb   = qbuf + 2*E;                    // E
  bf16*  khb   = qbuf + 3*E;                    // E
  bf16*  vtb   = qbuf + 4*E;                    // E
  bf16*  glbuf = (bf16*)BIGb;                   // ROWS*FFI (q..vt dead by then)
  float* wP    = (float*)BIGb;                  // wo partials 2E f32
  float* fP    = (float*)(BIGb + 16777216);     // ff2 partials 2E f32 (tail
                                                //   spills into dead wqT..woT,
                                                //   rebuilt next layer)
  bf16*  wqT   = WT;                            // [768][768]
  bf16*  wkvT  = WT + 589824;                   // [1536][768]
  bf16*  woT   = WT + 1769472;                  // [768][768]
  bf16*  wff1T = WT + 2359296;                  // [4096][768] (interleaved a/g)
  bf16*  wff2T = WT + 5505024;                  // [768][2048]

  cast_kernel<<<1536, 256, 0, stream>>>(x_in, xw16);
  ln_kernel<<<ROWS, 256, 0, stream>>>(x_in, attn_gamma, nullptr, S_h);

  for (int i = 0; i < NDEPTH; ++i) {
    const float* xsrc = (i == 0) ? x_in : xw32;

    TDs5 td;
    td.d[0] = { wq   + (size_t)i*589824,  wqT,   768,  768,    0, 0 };
    td.d[1] = { wkv  + (size_t)i*1179648, wkvT,  768, 1536,  576, 0 };
    td.d[2] = { wo   + (size_t)i*589824,  woT,   768,  768, 1728, 0 };
    td.d[3] = { wff1 + (size_t)i*3145728, wff1T, 768, 4096, 2304, 1 };
    td.d[4] = { wff2 + (size_t)i*1572864, wff2T, 2048, 768, 5376, 0 };
    wtrans_kernel<<<6912, 256, 0, stream>>>(td);

    // q = LN_attn(x) @ wq ; k,v = x @ wkv (k compact, v transposed in-epilogue)
    qkv_kernel<<<dim3(12,32,2), 256, 0, stream>>>(S_h, xw16, wqT, wkvT, qbuf, kbuf, vtb);
    // rope(q,k) + l2norm + scale (8 folded into q)
    rope_kernel<<<ROWS, 384, 0, stream>>>(qbuf, kbuf, q_scale + i*DH, k_scale + i*DH, qhb, khb);
    // flash attention: QBLK=128, 8 waves, XCD-colocated heads
    attn_kernel<<<dim3(8,48), 512, 0, stream>>>(qhb, khb, vtb,
                                                q_scale + i*DH, k_scale + i*DH, S_h);
    // x = x + o @ wo (split-K=2) ; fused reduce + residual + ff-LN
    gemm_splitk_kernel<64,384,768><<<dim3(12,32,2), 256, 0, stream>>>(S_h, woT, wP, ROWS, DIM);
    redln_kernel<<<ROWS, 256, 0, stream>>>(wP, wP + E, xsrc, xw32, nullptr, nullptr,
                                           ff_gamma + i*DIM, ff_beta + i*DIM, S_h);
    // gl = a*gelu(g) fused in FF1 epilogue (256^2 2-phase kernel)
    gemm256_kernel<<<dim3(16,16), 512, 0, stream>>>(S_h, wff1T, glbuf, ROWS, 2*FFI);
    // x = x + gl @ wff2 (split-K=2) ; fused reduce + residual (+ next attn-LN)
    gemm_splitk_kernel<64,1024,2048><<<dim3(12,32,2), 256, 0, stream>>>(glbuf, wff2T, fP, ROWS, DIM);
    if (i < NDEPTH-1)
      redln_kernel<<<ROWS, 256, 0, stream>>>(fP, fP + E, xw32, xw32, xw16, nullptr,
                                             attn_gamma + (i+1)*DIM, nullptr, S_h);
    else
      redln_kernel<<<ROWS, 256, 0, stream>>>(fP, fP + E, xw32, nullptr, nullptr, outp,
                                             nullptr, nullptr, nullptr);
  }
}

// Round 12
// 877.252 us; speedup vs baseline: 1.0388x; 1.0388x over previous
//
#include <hip/hip_runtime.h>
#include <hip/hip_bf16.h>
#include <math.h>

typedef __hip_bfloat16 bf16;
typedef __bf16 bf16x8 __attribute__((ext_vector_type(8)));
typedef float f32x4 __attribute__((ext_vector_type(4)));

#define NDEPTH 4
#define DIM 768
#define HEADS 12
#define DH 64
#define INNER 768
#define FFI 2048
#define BB 4
#define NN 1024
#define ROWS (BB*NN)   // 4096

__device__ __forceinline__ void async_cp16(const bf16* g, bf16* l) {
  __builtin_amdgcn_global_load_lds(
      (const __attribute__((address_space(1))) unsigned int*)g,
      (__attribute__((address_space(3))) unsigned int*)l, 16, 0, 0);
}

// ---------------------------------------------------------------------------
// bf16 MFMA GEMM body (R1 config — measured best for the N<=1536 GEMMs).
// C[MxN] = A[MxK] @ Bt[NxK]^T. 128xBN tile, BK=64, 4 waves, XOR-swizzled LDS
// (0 bank conflicts measured). 2-phase double-buffered pipeline.
// GEMM-plateau history: 6 structural variants (R2,R3,R4,R5,R7/R8) all
// null/negative -> ~500 TF is this small-K regime's plateau; R9+ strategy =
// remove work.
// R12: QROPE / VOUT-K epilogues fuse RoPE + head-L2-norm + per-dim scale
// directly into the GEMM output (kills rope_kernel + qbuf/kbuf round trip,
// ~25 MB/layer). Requires WN==64 (wave col span == one head) so the norm is
// a within-wave shfl reduction; rotation pairs are adjacent lanes
// (shfl_xor 1); rotation preserves pair norms so order is free.
// rtab: precomputed (cos,sin) table [n][32 pairs], f32.
// ---------------------------------------------------------------------------
template<int BN, bool GELU, bool VOUT, bool QROPE, int K, int LD>
__device__ __forceinline__ void gemm_body(
    const bf16* __restrict__ A, const bf16* __restrict__ Bt,
    bf16* __restrict__ Cb, float* __restrict__ Cf, const float* __restrict__ Rf,
    bf16* __restrict__ Vt, const float* __restrict__ rtab,
    const float* __restrict__ sc, bf16* __restrict__ Hout,
    int M, int N, int bx, int by, bf16* As, bf16* Bs)
{
  constexpr int WN = BN / 2;      // wave col extent
  constexpr int NT = WN / 16;     // col MFMA tiles per wave
  static_assert(WN == 64 || !(QROPE || VOUT), "rope/V epilogue needs WN==64");
  const int tid  = threadIdx.x;
  const int lane = tid & 63, w = tid >> 6;
  const int quad = lane >> 4, l16 = lane & 15;
  const int wr = w >> 1, wc = w & 1;
  const int m0 = by * 128, n0 = bx * BN;

  f32x4 acc[4][NT] = {};

  constexpr int CHA = 128 * 8;    // A chunks (8 x 16B per 64-elem row)
  constexpr int CH  = CHA + BN * 8;
  constexpr int NCH = CH / 256;   // chunks per thread
  constexpr int NTK = K / 64;     // K-steps

  auto stage = [&](int kk, int buf) {
    bf16* Asb = As + buf * (128*64);
    bf16* Bsb = Bs + buf * (BN*64);
    #pragma unroll
    for (int t = 0; t < NCH; ++t) {
      int c0 = w*64 + t*256;      // wave-uniform LDS base chunk
      int ch = c0 + lane;
      if (c0 < CHA) {
        int r = ch >> 3, j = (ch & 7) ^ (r & 7);
        async_cp16(&A[(size_t)(m0 + r)*LD + kk + j*8], &Asb[(size_t)c0*8]);
      } else {
        int ch2 = ch - CHA, r = ch2 >> 3, j = (ch2 & 7) ^ (r & 7);
        async_cp16(&Bt[(size_t)(n0 + r)*LD + kk + j*8], &Bsb[(size_t)(c0 - CHA)*8]);
      }
    }
  };

  stage(0, 0);
  __syncthreads();   // vmcnt(0) drain + barrier

  #pragma unroll
  for (int t = 0; t < NTK; ++t) {
    const int buf = t & 1;
    if (t + 1 < NTK) stage((t + 1) * 64, buf ^ 1);

    const bf16* Asb = As + buf * (128*64);
    const bf16* Bsb = Bs + buf * (BN*64);

    #pragma unroll
    for (int kc = 0; kc < 2; ++kc) {
      bf16x8 bfr[NT];
      #pragma unroll
      for (int nt = 0; nt < NT; ++nt) {
        int rb = wc*WN + nt*16 + l16;
        int c  = (kc*4 + quad) ^ (rb & 7);
        bfr[nt] = *(const bf16x8*)&Bsb[rb*64 + c*8];
      }
      #pragma unroll
      for (int mt = 0; mt < 4; ++mt) {
        int ra = wr*64 + mt*16 + l16;
        int ca = (kc*4 + quad) ^ (ra & 7);
        bf16x8 af = *(const bf16x8*)&Asb[ra*64 + ca*8];
        #pragma unroll
        for (int nt = 0; nt < NT; ++nt)
          acc[mt][nt] = __builtin_amdgcn_mfma_f32_16x16x32_bf16(af, bfr[nt], acc[mt][nt], 0, 0, 0);
      }
    }
    if (t + 1 < NTK) __syncthreads();
  }

  if constexpr (QROPE || VOUT) {
    const int cw = n0 + wc*64;                 // wave col base (one head span)
    if (QROPE || cw < INNER) {
      // --- rope + head-L2-norm + per-dim scale -> Hout (b,h,n,dh) ---
      const int hh = cw >> 6;
      const float S = QROPE ? 8.f : 1.f;       // ATTN_SCALE folded into q
      float scd[NT];
      #pragma unroll
      for (int nt = 0; nt < NT; ++nt) scd[nt] = sc[nt*16 + l16];
      #pragma unroll
      for (int mt = 0; mt < 4; ++mt) {
        float rot[NT][4];
        float ns[4] = {0.f, 0.f, 0.f, 0.f};
        #pragma unroll
        for (int nt = 0; nt < NT; ++nt) {
          int d = nt*16 + l16;
          #pragma unroll
          for (int r = 0; r < 4; ++r) {
            float v = acc[mt][nt][r];
            float p = __shfl_xor(v, 1);        // pair partner (d ^ 1)
            int row = m0 + wr*64 + mt*16 + quad*4 + r;
            int n = row & 1023;
            float2 cssn = ((const float2*)rtab)[n*32 + (d >> 1)];
            // even d: re*c - im*s ; odd d: re*s + im*c
            float rv = (l16 & 1) ? (p*cssn.y + v*cssn.x)
                                 : (v*cssn.x - p*cssn.y);
            rot[nt][r] = rv;
            ns[r] += rv*rv;
          }
        }
        #pragma unroll
        for (int r = 0; r < 4; ++r) {
          float s2 = ns[r];
          #pragma unroll
          for (int off = 1; off < 16; off <<= 1) s2 += __shfl_xor(s2, off);
          ns[r] = S / fmaxf(sqrtf(s2), 1e-12f);
        }
        #pragma unroll
        for (int nt = 0; nt < NT; ++nt) {
          int d = nt*16 + l16;
          #pragma unroll
          for (int r = 0; r < 4; ++r) {
            int row = m0 + wr*64 + mt*16 + quad*4 + r;
            int b = row >> 10, n = row & 1023;
            Hout[(((size_t)b*HEADS + hh)*NN + n)*DH + d] =
                __float2bfloat16(rot[nt][r] * ns[r] * scd[nt]);
          }
        }
      }
    } else {
      // --- V half -> (b,h,dh,n) packed 8B (unchanged) ---
      #pragma unroll
      for (int mt = 0; mt < 4; ++mt) {
        #pragma unroll
        for (int nt = 0; nt < NT; ++nt) {
          int row = m0 + wr*64 + mt*16 + quad*4;
          int col = n0 + wc*64 + nt*16 + l16;
          int c2 = col - INNER, hh2 = c2 >> 6, d = c2 & 63;
          int b = row >> 10, nn = row & 1023;
          union { ushort4 u4; bf16 h4[4]; } p;
          #pragma unroll
          for (int r = 0; r < 4; ++r) p.h4[r] = __float2bfloat16(acc[mt][nt][r]);
          *(ushort4*)&Vt[(((size_t)b*HEADS + hh2)*DH + d)*NN + nn] = p.u4;
        }
      }
    }
  } else {
    #pragma unroll
    for (int mt = 0; mt < 4; ++mt) {
      #pragma unroll
      for (int nt = 0; nt < NT; ++nt) {
        int row = m0 + wr*64 + mt*16 + quad*4;
        int col = n0 + wc*WN + nt*16 + l16;
        if (GELU) {
          #pragma unroll
          for (int r = 0; r < 4; ++r) {
            float v = acc[mt][nt][r];
            float g = __shfl_xor(v, 1);          // even lane: v=a, g from odd
            if (!(lane & 1)) {
              float ge = 0.5f * g * (1.f + erff(g * 0.70710678118654752f));
              Cb[(size_t)(row + r)*(N >> 1) + (col >> 1)] = __float2bfloat16(v * ge);
            }
          }
        } else {
          #pragma unroll
          for (int r = 0; r < 4; ++r) {
            float v = acc[mt][nt][r];
            size_t idx = (size_t)(row + r) * N + col;
            if (Rf) v += Rf[idx];
            if (Cf) Cf[idx] = v;
            if (Cb) Cb[idx] = __float2bfloat16(v);
          }
        }
      }
    }
  }
}

// Split-K=2: z selects K-half; partials to P[z*M*N]
template<int BN, int KH, int LD>
__global__ __launch_bounds__(256) void gemm_splitk_kernel(
    const bf16* __restrict__ A, const bf16* __restrict__ Bt,
    float* __restrict__ P, int M, int N)
{
  __shared__ __align__(16) bf16 As[2*128*64];
  __shared__ __align__(16) bf16 Bs[2*BN*64];
  const int z = blockIdx.z;
  gemm_body<BN,false,false,false,KH,LD>(A + (size_t)z*KH, Bt + (size_t)z*KH, nullptr,
                                        P + (size_t)z*M*N, nullptr, nullptr,
                                        nullptr, nullptr, nullptr,
                                        M, N, blockIdx.x, blockIdx.y, As, Bs);
}

// q = LN(x) @ wq with fused rope->qhb (BN=128, bx<6);
// kv = x @ wkv: K-half fused rope->khb, V-half transposed->vt (BN=128)
__global__ __launch_bounds__(256) void qkv_kernel(
    const bf16* __restrict__ h, const bf16* __restrict__ x16,
    const bf16* __restrict__ wqT, const bf16* __restrict__ wkvT,
    const float* __restrict__ rtab,
    const float* __restrict__ qsc, const float* __restrict__ ksc,
    bf16* __restrict__ qh, bf16* __restrict__ kh, bf16* __restrict__ vt)
{
  __shared__ __align__(16) bf16 As[2*128*64];
  __shared__ __align__(16) bf16 Bs[2*128*64];
  if (blockIdx.z == 0) {
    if (blockIdx.x >= 6) return;     // q: N=768 at BN=128 -> 6 bx
    gemm_body<128,false,false,true,768,768>(h, wqT, nullptr, nullptr, nullptr,
                                            nullptr, rtab, qsc, qh,
                                            ROWS, INNER, blockIdx.x, blockIdx.y, As, Bs);
  } else {
    gemm_body<128,false,true,false,768,768>(x16, wkvT, nullptr, nullptr, nullptr,
                                            vt, rtab, ksc, kh,
                                            ROWS, 2*INNER, blockIdx.x, blockIdx.y, As, Bs);
  }
}

// ---------------------------------------------------------------------------
// RoPE cos/sin table: tab[n][pr] = (cos, sin) of angle(n, pr), 1024 x 32 f32x2
// ---------------------------------------------------------------------------
__global__ __launch_bounds__(256) void ropetab_kernel(float* __restrict__ tab)
{
  int idx = blockIdx.x*256 + threadIdx.x;   // 32768 entries
  int n = idx >> 5, pr = idx & 31;
  float xp = (float)(n & 31), yp = (float)((n >> 5) & 31);
  int t = pr >> 1;
  float freq = powf(10000.f, -(float)t / 16.f);
  float ang = (pr & 1) ? yp * freq : xp * freq;
  float sn, cs;
  sincosf(ang, &sn, &cs);
  ((float2*)tab)[idx] = make_float2(cs, sn);
}

// ---------------------------------------------------------------------------
// 256x256 8-wave GEMM + GELU for FF1 (M=N=4096, K=768). R6 2-PHASE form
// (measured 50.0us — best). 2D-region XCD swizzle kept (FETCH 28->19MB).
// ---------------------------------------------------------------------------
__global__ __launch_bounds__(512) void gemm256_kernel(
    const bf16* __restrict__ A, const bf16* __restrict__ Bt,
    bf16* __restrict__ Cb, int M, int N)
{
  __shared__ __align__(16) bf16 As[2][256*64];
  __shared__ __align__(16) bf16 Bs[2][256*64];

  const int tid  = threadIdx.x;
  const int lane = tid & 63, wv = tid >> 6;
  const int quad = lane >> 4, l16 = lane & 15;
  const int wr = wv >> 2, wc = wv & 3;          // 2 x 4 wave grid

  // 2D-region XCD swizzle (bijective for the 16x16 grid)
  const int lin = blockIdx.y * gridDim.x + blockIdx.x;
  const int xcd = lin & 7, loc = lin >> 3;
  const int bxs = (xcd & 1) * 8 + (loc & 7);
  const int bys = (xcd >> 1) * 4 + (loc >> 3);
  const int m0 = bys * 256, n0 = bxs * 256;

  f32x4 acc[8][4] = {};

  auto stage = [&](int kk, int buf) {
    #pragma unroll
    for (int t = 0; t < 8; ++t) {
      int c0 = wv*64 + t*512;                   // wave-uniform base chunk
      int ch = c0 + lane;
      if (c0 < 2048) {
        int r = ch >> 3, j = (ch & 7) ^ (r & 7);
        async_cp16(&A[(size_t)(m0 + r)*768 + kk + j*8], &As[buf][(size_t)c0*8]);
      } else {
        int ch2 = ch - 2048, r = ch2 >> 3, j = (ch2 & 7) ^ (r & 7);
        async_cp16(&Bt[(size_t)(n0 + r)*768 + kk + j*8], &Bs[buf][(size_t)(c0 - 2048)*8]);
      }
    }
  };

  stage(0, 0);
  __syncthreads();

  #pragma unroll
  for (int t = 0; t < 12; ++t) {                // K = 768 = 12 x 64
    const int buf = t & 1;
    if (t + 1 < 12) stage((t + 1) * 64, buf ^ 1);

    const bf16* Asb = &As[buf][0];
    const bf16* Bsb = &Bs[buf][0];

    #pragma unroll
    for (int kc = 0; kc < 2; ++kc) {
      bf16x8 bfr[4];
      #pragma unroll
      for (int nt = 0; nt < 4; ++nt) {
        int rb = wc*64 + nt*16 + l16;
        int c  = (kc*4 + quad) ^ (rb & 7);
        bfr[nt] = *(const bf16x8*)&Bsb[rb*64 + c*8];
      }
      #pragma unroll
      for (int mt = 0; mt < 8; ++mt) {
        int ra = wr*128 + mt*16 + l16;
        int ca = (kc*4 + quad) ^ (ra & 7);
        bf16x8 af = *(const bf16x8*)&Asb[ra*64 + ca*8];
        #pragma unroll
        for (int nt = 0; nt < 4; ++nt)
          acc[mt][nt] = __builtin_amdgcn_mfma_f32_16x16x32_bf16(af, bfr[nt], acc[mt][nt], 0, 0, 0);
      }
    }
    if (t + 1 < 12) __syncthreads();
  }

  // GELU epilogue: cols interleave (a,g); even lane holds a, odd holds g
  #pragma unroll
  for (int mt = 0; mt < 8; ++mt) {
    #pragma unroll
    for (int nt = 0; nt < 4; ++nt) {
      int row = m0 + wr*128 + mt*16 + quad*4;
      int col = n0 + wc*64 + nt*16 + l16;
      #pragma unroll
      for (int r = 0; r < 4; ++r) {
        float v = acc[mt][nt][r];
        float g = __shfl_xor(v, 1);
        if (!(lane & 1)) {
          float ge = 0.5f * g * (1.f + erff(g * 0.70710678118654752f));
          Cb[(size_t)(row + r)*(N >> 1) + (col >> 1)] = __float2bfloat16(v * ge);
        }
      }
    }
  }
}

// ---------------------------------------------------------------------------
// LayerNorm (row = 768, f32 in, bf16 out) — used once for layer-0 attn-LN
// ---------------------------------------------------------------------------
__global__ __launch_bounds__(256) void ln_kernel(
    const float* __restrict__ x, const float* __restrict__ g,
    const float* __restrict__ bta, bf16* __restrict__ out)
{
  const int row = blockIdx.x, tid = threadIdx.x;
  const size_t base = (size_t)row * DIM;
  float v[3];
  #pragma unroll
  for (int j = 0; j < 3; ++j) v[j] = x[base + tid + j*256];
  float s  = v[0] + v[1] + v[2];
  float ss = v[0]*v[0] + v[1]*v[1] + v[2]*v[2];
  #pragma unroll
  for (int off = 32; off; off >>= 1) { s += __shfl_xor(s, off); ss += __shfl_xor(ss, off); }
  __shared__ float red[8];
  int w = tid >> 6;
  if ((tid & 63) == 0) { red[w] = s; red[w + 4] = ss; }
  __syncthreads();
  s  = red[0] + red[1] + red[2] + red[3];
  ss = red[4] + red[5] + red[6] + red[7];
  float mean = s * (1.f/768.f);
  float var  = ss * (1.f/768.f) - mean*mean;
  float rstd = rsqrtf(fmaxf(var, 0.f) + 1e-5f);
  #pragma unroll
  for (int j = 0; j < 3; ++j) {
    int c = tid + j*256;
    float bv = bta ? bta[c] : 0.f;
    out[base + c] = __float2bfloat16((v[j] - mean) * rstd * g[c] + bv);
  }
}

// ---------------------------------------------------------------------------
// Split-K reduce + residual + optional LN (fused). Row = 768.
// ---------------------------------------------------------------------------
__global__ __launch_bounds__(256) void redln_kernel(
    const float* __restrict__ P0, const float* __restrict__ P1,
    const float* __restrict__ res,
    float* __restrict__ xo32, bf16* __restrict__ xo16, float* __restrict__ outf,
    const float* __restrict__ g, const float* __restrict__ bta,
    bf16* __restrict__ lnout)
{
  const int row = blockIdx.x, tid = threadIdx.x;
  const size_t base = (size_t)row * DIM;
  float v[3];
  #pragma unroll
  for (int j = 0; j < 3; ++j) {
    size_t idx = base + tid + j*256;
    v[j] = res[idx] + P0[idx] + P1[idx];
    if (xo32) xo32[idx] = v[j];
    if (xo16) xo16[idx] = __float2bfloat16(v[j]);
    if (outf) outf[idx] = v[j];
  }
  if (!g) return;
  float s  = v[0] + v[1] + v[2];
  float ss = v[0]*v[0] + v[1]*v[1] + v[2]*v[2];
  #pragma unroll
  for (int off = 32; off; off >>= 1) { s += __shfl_xor(s, off); ss += __shfl_xor(ss, off); }
  __shared__ float red[8];
  int w = tid >> 6;
  if ((tid & 63) == 0) { red[w] = s; red[w + 4] = ss; }
  __syncthreads();
  s  = red[0] + red[1] + red[2] + red[3];
  ss = red[4] + red[5] + red[6] + red[7];
  float mean = s * (1.f/768.f);
  float var  = ss * (1.f/768.f) - mean*mean;
  float rstd = rsqrtf(fmaxf(var, 0.f) + 1e-5f);
  #pragma unroll
  for (int j = 0; j < 3; ++j) {
    int c = tid + j*256;
    float bv = bta ? bta[c] : 0.f;
    lnout[base + c] = __float2bfloat16((v[j] - mean) * rstd * g[c] + bv);
  }
}

// ---------------------------------------------------------------------------
// Flash attention — R10 champion form (QBLK=64, 256 thr, async
// global_load_lds double-buffer, XOR-swizzled LDS, setprio on MFMA).
// (R11's QBLK=128 + XCD-colocate bundle measured neutral; reverted.)
// ---------------------------------------------------------------------------
__global__ __launch_bounds__(256) void attn_kernel(
    const bf16* __restrict__ qh, const bf16* __restrict__ kh,
    const bf16* __restrict__ vt, const float* __restrict__ qsc,
    const float* __restrict__ ksc, bf16* __restrict__ ob)
{
  __shared__ __align__(16) bf16 Qs[64*64];
  __shared__ __align__(16) bf16 Ks[2][64*64];
  __shared__ __align__(16) bf16 Vs[2][64*64];
  __shared__ __align__(16) bf16 Ps[4][16*72];

  const int tid = threadIdx.x;
  const int lane = tid & 63, w = tid >> 6;
  const int quad = lane >> 4, l16 = lane & 15;
  const int qt = blockIdx.x, bh = blockIdx.y;
  const int b = bh / HEADS, h = bh % HEADS;
  const size_t base = (size_t)bh * NN * DH;

  float mq = fabsf(qsc[lane]), mk = fabsf(ksc[lane]);
  #pragma unroll
  for (int off = 1; off < 64; off <<= 1) {
    mq = fmaxf(mq, __shfl_xor(mq, off));
    mk = fmaxf(mk, __shfl_xor(mk, off));
  }
  const float Mb = 8.f * mq * mk;

  // stage Q once (512 chunks, 2/thread), pre-swizzled source -> linear dest
  #pragma unroll
  for (int t = 0; t < 2; ++t) {
    int c0 = w*64 + t*256, ch = c0 + lane;
    int r = ch >> 3, jl = (ch & 7) ^ (r & 7);
    async_cp16(&qh[base + (size_t)(qt*64 + r)*64 + jl*8], &Qs[(size_t)c0*8]);
  }

  // stage one K/V tile (1024 chunks, 4/thread) into buffer buf
  auto stage_kv = [&](int kt0, int buf) {
    #pragma unroll
    for (int t = 0; t < 4; ++t) {
      int c0 = w*64 + t*256, ch = c0 + lane;
      if (c0 < 512) {            // K: rows = n, cols = dh
        int r = ch >> 3, jl = (ch & 7) ^ (r & 7);
        async_cp16(&kh[base + (size_t)(kt0*64 + r)*64 + jl*8],
                   &Ks[buf][(size_t)c0*8]);
      } else {                   // V: rows = dh, cols = n (vt is (b,h,dh,n))
        int ch2 = ch - 512, r = ch2 >> 3, jl = (ch2 & 7) ^ (r & 7);
        async_cp16(&vt[base + (size_t)r*NN + kt0*64 + jl*8],
                   &Vs[buf][(size_t)(c0 - 512)*8]);
      }
    }
  };

  f32x4 o[4] = {};
  float pl[4] = {0.f, 0.f, 0.f, 0.f};

  stage_kv(0, 0);
  __syncthreads();               // drains Q + tile-0 loads

  for (int kt0 = 0; kt0 < NN/64; ++kt0) {
    const int buf = kt0 & 1;
    if (kt0 + 1 < NN/64) stage_kv(kt0 + 1, buf ^ 1);  // async, hides under MFMA

    f32x4 s[4] = {};
    bf16x8 aq[2];
    const int rq = w*16 + l16;
    #pragma unroll
    for (int kc = 0; kc < 2; ++kc)
      aq[kc] = *(const bf16x8*)&Qs[rq*64 + ((kc*4 + quad) ^ (rq & 7))*8];
    __builtin_amdgcn_s_setprio(1);
    #pragma unroll
    for (int kt = 0; kt < 4; ++kt)
      #pragma unroll
      for (int kc = 0; kc < 2; ++kc) {
        int rb = kt*16 + l16;
        bf16x8 bk = *(const bf16x8*)&Ks[buf][rb*64 + ((kc*4 + quad) ^ (rb & 7))*8];
        s[kt] = __builtin_amdgcn_mfma_f32_16x16x32_bf16(aq[kc], bk, s[kt], 0, 0, 0);
      }
    __builtin_amdgcn_s_setprio(0);

    #pragma unroll
    for (int r = 0; r < 4; ++r) {
      #pragma unroll
      for (int kt = 0; kt < 4; ++kt) {
        float pv = __expf(s[kt][r] - Mb);
        pl[r] += pv;
        Ps[w][(quad*4 + r)*72 + kt*16 + l16] = __float2bfloat16(pv);
      }
    }
    // no barrier: Ps[w] is produced and consumed by the same wave.

    __builtin_amdgcn_s_setprio(1);
    #pragma unroll
    for (int kc = 0; kc < 2; ++kc) {
      bf16x8 ap = *(const bf16x8*)&Ps[w][l16*72 + kc*32 + quad*8];
      #pragma unroll
      for (int nt = 0; nt < 4; ++nt) {
        int rv = nt*16 + l16;
        bf16x8 bv = *(const bf16x8*)&Vs[buf][rv*64 + ((kc*4 + quad) ^ (rv & 7))*8];
        o[nt] = __builtin_amdgcn_mfma_f32_16x16x32_bf16(ap, bv, o[nt], 0, 0, 0);
      }
    }
    __builtin_amdgcn_s_setprio(0);

    if (kt0 + 1 < NN/64) __syncthreads();
  }

  float l[4];
  #pragma unroll
  for (int r = 0; r < 4; ++r) {
    float rs = pl[r];
    #pragma unroll
    for (int off = 1; off < 16; off <<= 1) rs += __shfl_xor(rs, off);
    l[r] = rs;
  }

  #pragma unroll
  for (int nt = 0; nt < 4; ++nt)
    #pragma unroll
    for (int r = 0; r < 4; ++r) {
      int n = qt*64 + w*16 + quad*4 + r;
      int dcol = nt*16 + l16;
      ob[((size_t)(b*NN + n)*HEADS + h)*DH + dcol] = __float2bfloat16(o[nt][r] / l[r]);
    }
}

// ---------------------------------------------------------------------------
// f32 -> bf16 cast (vectorized x8)
// ---------------------------------------------------------------------------
__global__ __launch_bounds__(256) void cast_kernel(
    const float* __restrict__ x, bf16* __restrict__ o)
{
  size_t i = ((size_t)blockIdx.x*256 + threadIdx.x) * 8;
  float4 f0 = *(const float4*)(x + i);
  float4 f1 = *(const float4*)(x + i + 4);
  union { uint4 u; bf16 h[8]; } p;
  p.h[0] = __float2bfloat16(f0.x); p.h[1] = __float2bfloat16(f0.y);
  p.h[2] = __float2bfloat16(f0.z); p.h[3] = __float2bfloat16(f0.w);
  p.h[4] = __float2bfloat16(f1.x); p.h[5] = __float2bfloat16(f1.y);
  p.h[6] = __float2bfloat16(f1.z); p.h[7] = __float2bfloat16(f1.w);
  *(uint4*)(o + i) = p.u;
}

// ---------------------------------------------------------------------------
// Fused weight transpose: 5 weights f32 (RxC) -> bf16 (CxR), one dispatch.
// perm=1 (wff1): output rows interleave a/g columns.
// ---------------------------------------------------------------------------
struct TD { const float* src; bf16* dst; int R, C, base, perm; };
struct TDs5 { TD d[5]; };

__global__ __launch_bounds__(256) void wtrans_kernel(TDs5 a)
{
  const int blk = blockIdx.x;
  int di = 0;
  #pragma unroll
  for (int k = 1; k < 5; ++k) if (blk >= a.d[k].base) di = k;
  const TD d = a.d[di];
  const int local = blk - d.base;
  const int tilesX = d.C >> 5;
  const int by = local / tilesX, bx = local - by*tilesX;
  __shared__ float t[32][33];
  const int tx = threadIdx.x & 31, ty = threadIdx.x >> 5;
  const int c0 = bx*32, r0 = by*32;
  #pragma unroll
  for (int i = 0; i < 4; ++i)
    t[ty + i*8][tx] = d.src[(size_t)(r0 + ty + i*8)*d.C + c0 + tx];
  __syncthreads();
  const int half = d.C >> 1;
  #pragma unroll
  for (int i = 0; i < 4; ++i) {
    int c = c0 + ty + i*8;
    int rout = d.perm ? ((c < half) ? 2*c : 2*(c - half) + 1) : c;
    d.dst[(size_t)rout*d.R + r0 + tx] = __float2bfloat16(t[tx][ty + i*8]);
  }
}

// ---------------------------------------------------------------------------
extern "C" void kernel_launch(void* const* d_in, const int* in_sizes, int n_in,
                              void* d_out, int out_size, void* d_ws, size_t ws_size,
                              hipStream_t stream)
{
  const float* x_in       = (const float*)d_in[0];
  const float* attn_gamma = (const float*)d_in[1];
  const float* wq         = (const float*)d_in[2];
  const float* wkv        = (const float*)d_in[3];
  const float* q_scale    = (const float*)d_in[4];
  const float* k_scale    = (const float*)d_in[5];
  const float* wo         = (const float*)d_in[6];
  const float* ff_gamma   = (const float*)d_in[7];
  const float* ff_beta    = (const float*)d_in[8];
  const float* wff1       = (const float*)d_in[9];
  const float* wff2       = (const float*)d_in[10];
  float* outp = (float*)d_out;
  char* ws = (char*)d_ws;

  const size_t E = (size_t)ROWS * DIM;      // 3,145,728 elems
  float* xw32 = (float*)ws;                     // [0, 12.58M) f32 residual
  bf16*  xw16 = (bf16*)(ws + 12582912);         // bf16 shadow (kv input)
  bf16*  S_h  = (bf16*)(ws + 18874368);         // LN out / attn out
  char*  BIGb = ws + 25165824;                  // 37.75M scratch
  bf16*  WT   = (bf16*)(ws + 62914560);         // transposed weights
  bf16*  qbuf  = (bf16*)BIGb;                   // (dead: rope fused) E elems
  bf16*  qhb   = qbuf + 2*E;                    // E
  bf16*  khb   = qbuf + 3*E;                    // E
  bf16*  vtb   = qbuf + 4*E;                    // E
  bf16*  glbuf = (bf16*)BIGb;                   // ROWS*FFI (q..vt dead by then)
  float* wP    = (float*)BIGb;                  // wo partials 2E f32
  float* fP    = (float*)(BIGb + 16777216);     // ff2 partials 2E f32 (tail
                                                //   spills into dead wqT..woT,
                                                //   rebuilt next layer)
  bf16*  wqT   = WT;                            // [768][768]
  bf16*  wkvT  = WT + 589824;                   // [1536][768]
  bf16*  woT   = WT + 1769472;                  // [768][768]
  bf16*  wff1T = WT + 2359296;                  // [4096][768] (interleaved a/g)
  bf16*  wff2T = WT + 5505024;                  // [768][2048]

  // RoPE table: after WT if workspace allows (built once), else in BIGb
  // (clobbered by wP each layer -> rebuilt per layer).
  const size_t rtab_off = 77070336;             // WT end
  const bool tonce = ws_size >= rtab_off + 262144;
  float* rtab = tonce ? (float*)(ws + rtab_off) : (float*)BIGb;

  cast_kernel<<<1536, 256, 0, stream>>>(x_in, xw16);
  ln_kernel<<<ROWS, 256, 0, stream>>>(x_in, attn_gamma, nullptr, S_h);
  if (tonce) ropetab_kernel<<<128, 256, 0, stream>>>(rtab);

  for (int i = 0; i < NDEPTH; ++i) {
    const float* xsrc = (i == 0) ? x_in : xw32;

    TDs5 td;
    td.d[0] = { wq   + (size_t)i*589824,  wqT,   768,  768,    0, 0 };
    td.d[1] = { wkv  + (size_t)i*1179648, wkvT,  768, 1536,  576, 0 };
    td.d[2] = { wo   + (size_t)i*589824,  woT,   768,  768, 1728, 0 };
    td.d[3] = { wff1 + (size_t)i*3145728, wff1T, 768, 4096, 2304, 1 };
    td.d[4] = { wff2 + (size_t)i*1572864, wff2T, 2048, 768, 5376, 0 };
    wtrans_kernel<<<6912, 256, 0, stream>>>(td);
    if (!tonce) ropetab_kernel<<<128, 256, 0, stream>>>(rtab);

    // q/k: GEMM + fused rope+l2norm+scale -> qhb/khb ; v transposed -> vtb
    qkv_kernel<<<dim3(12,32,2), 256, 0, stream>>>(S_h, xw16, wqT, wkvT, rtab,
                                                  q_scale + i*DH, k_scale + i*DH,
                                                  qhb, khb, vtb);
    attn_kernel<<<dim3(16,48), 256, 0, stream>>>(qhb, khb, vtb,
                                                 q_scale + i*DH, k_scale + i*DH, S_h);
    // x = x + o @ wo (split-K=2) ; fused reduce + residual + ff-LN
    gemm_splitk_kernel<64,384,768><<<dim3(12,32,2), 256, 0, stream>>>(S_h, woT, wP, ROWS, DIM);
    redln_kernel<<<ROWS, 256, 0, stream>>>(wP, wP + E, xsrc, xw32, nullptr, nullptr,
                                           ff_gamma + i*DIM, ff_beta + i*DIM, S_h);
    // gl = a*gelu(g) fused in FF1 epilogue (256^2 2-phase kernel)
    gemm256_kernel<<<dim3(16,16), 512, 0, stream>>>(S_h, wff1T, glbuf, ROWS, 2*FFI);
    // x = x + gl @ wff2 (split-K=2) ; fused reduce + residual (+ next attn-LN)
    gemm_splitk_kernel<64,1024,2048><<<dim3(12,32,2), 256, 0, stream>>>(glbuf, wff2T, fP, ROWS, DIM);
    if (i < NDEPTH-1)
      redln_kernel<<<ROWS, 256, 0, stream>>>(fP, fP + E, xw32, xw32, xw16, nullptr,
                                             attn_gamma + (i+1)*DIM, nullptr, S_h);
    else
      redln_kernel<<<ROWS, 256, 0, stream>>>(fP, fP + E, xw32, nullptr, nullptr, outp,
                                             nullptr, nullptr, nullptr);
  }
}

// Round 13
// 873.237 us; speedup vs baseline: 1.0436x; 1.0046x over previous
//
#include <hip/hip_runtime.h>
#include <hip/hip_bf16.h>
#include <math.h>

typedef __hip_bfloat16 bf16;
typedef __bf16 bf16x8 __attribute__((ext_vector_type(8)));
typedef float f32x4 __attribute__((ext_vector_type(4)));

#define NDEPTH 4
#define DIM 768
#define HEADS 12
#define DH 64
#define INNER 768
#define FFI 2048
#define BB 4
#define NN 1024
#define ROWS (BB*NN)   // 4096

__device__ __forceinline__ void async_cp16(const bf16* g, bf16* l) {
  __builtin_amdgcn_global_load_lds(
      (const __attribute__((address_space(1))) unsigned int*)g,
      (__attribute__((address_space(3))) unsigned int*)l, 16, 0, 0);
}

// ---------------------------------------------------------------------------
// bf16 MFMA GEMM body (R1 config — measured best for the N<=1536 GEMMs).
// C[MxN] = A[MxK] @ Bt[NxK]^T. 128xBN tile, BK=64, 4 waves, XOR-swizzled LDS
// (0 bank conflicts measured). 2-phase double-buffered pipeline.
// GEMM-plateau history: 6 structural variants (R2,R3,R4,R5,R7/R8) all
// null/negative -> ~500 TF is this small-K regime's plateau; strategy since
// R9 = remove work, not schedule.
// R12: QROPE / VOUT-K epilogues fuse RoPE + head-L2-norm + per-dim scale
// directly into the GEMM output (killed rope_kernel + qbuf/kbuf round trip,
// ~25 MB/layer; measured -30us total). Requires WN==64 (wave col span ==
// one head) so the norm is a within-wave shfl reduction; rotation pairs are
// adjacent lanes (shfl_xor 1); rotation preserves pair norms so order free.
// rtab: precomputed (cos,sin) table [n][32 pairs], f32.
// ---------------------------------------------------------------------------
template<int BN, bool GELU, bool VOUT, bool QROPE, int K, int LD>
__device__ __forceinline__ void gemm_body(
    const bf16* __restrict__ A, const bf16* __restrict__ Bt,
    bf16* __restrict__ Cb, float* __restrict__ Cf, const float* __restrict__ Rf,
    bf16* __restrict__ Vt, const float* __restrict__ rtab,
    const float* __restrict__ sc, bf16* __restrict__ Hout,
    int M, int N, int bx, int by, bf16* As, bf16* Bs)
{
  constexpr int WN = BN / 2;      // wave col extent
  constexpr int NT = WN / 16;     // col MFMA tiles per wave
  static_assert(WN == 64 || !(QROPE || VOUT), "rope/V epilogue needs WN==64");
  const int tid  = threadIdx.x;
  const int lane = tid & 63, w = tid >> 6;
  const int quad = lane >> 4, l16 = lane & 15;
  const int wr = w >> 1, wc = w & 1;
  const int m0 = by * 128, n0 = bx * BN;

  f32x4 acc[4][NT] = {};

  constexpr int CHA = 128 * 8;    // A chunks (8 x 16B per 64-elem row)
  constexpr int CH  = CHA + BN * 8;
  constexpr int NCH = CH / 256;   // chunks per thread
  constexpr int NTK = K / 64;     // K-steps

  auto stage = [&](int kk, int buf) {
    bf16* Asb = As + buf * (128*64);
    bf16* Bsb = Bs + buf * (BN*64);
    #pragma unroll
    for (int t = 0; t < NCH; ++t) {
      int c0 = w*64 + t*256;      // wave-uniform LDS base chunk
      int ch = c0 + lane;
      if (c0 < CHA) {
        int r = ch >> 3, j = (ch & 7) ^ (r & 7);
        async_cp16(&A[(size_t)(m0 + r)*LD + kk + j*8], &Asb[(size_t)c0*8]);
      } else {
        int ch2 = ch - CHA, r = ch2 >> 3, j = (ch2 & 7) ^ (r & 7);
        async_cp16(&Bt[(size_t)(n0 + r)*LD + kk + j*8], &Bsb[(size_t)(c0 - CHA)*8]);
      }
    }
  };

  stage(0, 0);
  __syncthreads();   // vmcnt(0) drain + barrier

  #pragma unroll
  for (int t = 0; t < NTK; ++t) {
    const int buf = t & 1;
    if (t + 1 < NTK) stage((t + 1) * 64, buf ^ 1);

    const bf16* Asb = As + buf * (128*64);
    const bf16* Bsb = Bs + buf * (BN*64);

    #pragma unroll
    for (int kc = 0; kc < 2; ++kc) {
      bf16x8 bfr[NT];
      #pragma unroll
      for (int nt = 0; nt < NT; ++nt) {
        int rb = wc*WN + nt*16 + l16;
        int c  = (kc*4 + quad) ^ (rb & 7);
        bfr[nt] = *(const bf16x8*)&Bsb[rb*64 + c*8];
      }
      #pragma unroll
      for (int mt = 0; mt < 4; ++mt) {
        int ra = wr*64 + mt*16 + l16;
        int ca = (kc*4 + quad) ^ (ra & 7);
        bf16x8 af = *(const bf16x8*)&Asb[ra*64 + ca*8];
        #pragma unroll
        for (int nt = 0; nt < NT; ++nt)
          acc[mt][nt] = __builtin_amdgcn_mfma_f32_16x16x32_bf16(af, bfr[nt], acc[mt][nt], 0, 0, 0);
      }
    }
    if (t + 1 < NTK) __syncthreads();
  }

  if constexpr (QROPE || VOUT) {
    const int cw = n0 + wc*64;                 // wave col base (one head span)
    if (QROPE || cw < INNER) {
      // --- rope + head-L2-norm + per-dim scale -> Hout (b,h,n,dh) ---
      const int hh = cw >> 6;
      const float S = QROPE ? 8.f : 1.f;       // ATTN_SCALE folded into q
      float scd[NT];
      #pragma unroll
      for (int nt = 0; nt < NT; ++nt) scd[nt] = sc[nt*16 + l16];
      #pragma unroll
      for (int mt = 0; mt < 4; ++mt) {
        float rot[NT][4];
        float ns[4] = {0.f, 0.f, 0.f, 0.f};
        #pragma unroll
        for (int nt = 0; nt < NT; ++nt) {
          int d = nt*16 + l16;
          #pragma unroll
          for (int r = 0; r < 4; ++r) {
            float v = acc[mt][nt][r];
            float p = __shfl_xor(v, 1);        // pair partner (d ^ 1)
            int row = m0 + wr*64 + mt*16 + quad*4 + r;
            int n = row & 1023;
            float2 cssn = ((const float2*)rtab)[n*32 + (d >> 1)];
            // even d: re*c - im*s ; odd d: re*s + im*c
            float rv = (l16 & 1) ? (p*cssn.y + v*cssn.x)
                                 : (v*cssn.x - p*cssn.y);
            rot[nt][r] = rv;
            ns[r] += rv*rv;
          }
        }
        #pragma unroll
        for (int r = 0; r < 4; ++r) {
          float s2 = ns[r];
          #pragma unroll
          for (int off = 1; off < 16; off <<= 1) s2 += __shfl_xor(s2, off);
          ns[r] = S / fmaxf(sqrtf(s2), 1e-12f);
        }
        #pragma unroll
        for (int nt = 0; nt < NT; ++nt) {
          int d = nt*16 + l16;
          #pragma unroll
          for (int r = 0; r < 4; ++r) {
            int row = m0 + wr*64 + mt*16 + quad*4 + r;
            int b = row >> 10, n = row & 1023;
            Hout[(((size_t)b*HEADS + hh)*NN + n)*DH + d] =
                __float2bfloat16(rot[nt][r] * ns[r] * scd[nt]);
          }
        }
      }
    } else {
      // --- V half -> (b,h,dh,n) packed 8B (unchanged) ---
      #pragma unroll
      for (int mt = 0; mt < 4; ++mt) {
        #pragma unroll
        for (int nt = 0; nt < NT; ++nt) {
          int row = m0 + wr*64 + mt*16 + quad*4;
          int col = n0 + wc*64 + nt*16 + l16;
          int c2 = col - INNER, hh2 = c2 >> 6, d = c2 & 63;
          int b = row >> 10, nn = row & 1023;
          union { ushort4 u4; bf16 h4[4]; } p;
          #pragma unroll
          for (int r = 0; r < 4; ++r) p.h4[r] = __float2bfloat16(acc[mt][nt][r]);
          *(ushort4*)&Vt[(((size_t)b*HEADS + hh2)*DH + d)*NN + nn] = p.u4;
        }
      }
    }
  } else {
    #pragma unroll
    for (int mt = 0; mt < 4; ++mt) {
      #pragma unroll
      for (int nt = 0; nt < NT; ++nt) {
        int row = m0 + wr*64 + mt*16 + quad*4;
        int col = n0 + wc*WN + nt*16 + l16;
        if (GELU) {
          #pragma unroll
          for (int r = 0; r < 4; ++r) {
            float v = acc[mt][nt][r];
            float g = __shfl_xor(v, 1);          // even lane: v=a, g from odd
            if (!(lane & 1)) {
              float ge = 0.5f * g * (1.f + erff(g * 0.70710678118654752f));
              Cb[(size_t)(row + r)*(N >> 1) + (col >> 1)] = __float2bfloat16(v * ge);
            }
          }
        } else {
          #pragma unroll
          for (int r = 0; r < 4; ++r) {
            float v = acc[mt][nt][r];
            size_t idx = (size_t)(row + r) * N + col;
            if (Rf) v += Rf[idx];
            if (Cf) Cf[idx] = v;
            if (Cb) Cb[idx] = __float2bfloat16(v);
          }
        }
      }
    }
  }
}

// Split-K=2: z selects K-half; partials to P[z*M*N]
template<int BN, int KH, int LD>
__global__ __launch_bounds__(256) void gemm_splitk_kernel(
    const bf16* __restrict__ A, const bf16* __restrict__ Bt,
    float* __restrict__ P, int M, int N)
{
  __shared__ __align__(16) bf16 As[2*128*64];
  __shared__ __align__(16) bf16 Bs[2*BN*64];
  const int z = blockIdx.z;
  gemm_body<BN,false,false,false,KH,LD>(A + (size_t)z*KH, Bt + (size_t)z*KH, nullptr,
                                        P + (size_t)z*M*N, nullptr, nullptr,
                                        nullptr, nullptr, nullptr,
                                        M, N, blockIdx.x, blockIdx.y, As, Bs);
}

// q = LN(x) @ wq with fused rope->qhb (BN=128, bx<6);
// kv = x @ wkv: K-half fused rope->khb, V-half transposed->vt (BN=128)
__global__ __launch_bounds__(256) void qkv_kernel(
    const bf16* __restrict__ h, const bf16* __restrict__ x16,
    const bf16* __restrict__ wqT, const bf16* __restrict__ wkvT,
    const float* __restrict__ rtab,
    const float* __restrict__ qsc, const float* __restrict__ ksc,
    bf16* __restrict__ qh, bf16* __restrict__ kh, bf16* __restrict__ vt)
{
  __shared__ __align__(16) bf16 As[2*128*64];
  __shared__ __align__(16) bf16 Bs[2*128*64];
  if (blockIdx.z == 0) {
    if (blockIdx.x >= 6) return;     // q: N=768 at BN=128 -> 6 bx
    gemm_body<128,false,false,true,768,768>(h, wqT, nullptr, nullptr, nullptr,
                                            nullptr, rtab, qsc, qh,
                                            ROWS, INNER, blockIdx.x, blockIdx.y, As, Bs);
  } else {
    gemm_body<128,false,true,false,768,768>(x16, wkvT, nullptr, nullptr, nullptr,
                                            vt, rtab, ksc, kh,
                                            ROWS, 2*INNER, blockIdx.x, blockIdx.y, As, Bs);
  }
}

// ---------------------------------------------------------------------------
// RoPE cos/sin table: tab[n][pr] = (cos, sin) of angle(n, pr), 1024 x 32 f32x2
// ---------------------------------------------------------------------------
__global__ __launch_bounds__(256) void ropetab_kernel(float* __restrict__ tab)
{
  int idx = blockIdx.x*256 + threadIdx.x;   // 32768 entries
  int n = idx >> 5, pr = idx & 31;
  float xp = (float)(n & 31), yp = (float)((n >> 5) & 31);
  int t = pr >> 1;
  float freq = powf(10000.f, -(float)t / 16.f);
  float ang = (pr & 1) ? yp * freq : xp * freq;
  float sn, cs;
  sincosf(ang, &sn, &cs);
  ((float2*)tab)[idx] = make_float2(cs, sn);
}

// ---------------------------------------------------------------------------
// 256x256 8-wave GEMM + GELU for FF1 (M=N=4096, K=768). R6 2-PHASE form
// (measured 50.0us — best). 2D-region XCD swizzle kept (FETCH 28->19MB).
// ---------------------------------------------------------------------------
__global__ __launch_bounds__(512) void gemm256_kernel(
    const bf16* __restrict__ A, const bf16* __restrict__ Bt,
    bf16* __restrict__ Cb, int M, int N)
{
  __shared__ __align__(16) bf16 As[2][256*64];
  __shared__ __align__(16) bf16 Bs[2][256*64];

  const int tid  = threadIdx.x;
  const int lane = tid & 63, wv = tid >> 6;
  const int quad = lane >> 4, l16 = lane & 15;
  const int wr = wv >> 2, wc = wv & 3;          // 2 x 4 wave grid

  // 2D-region XCD swizzle (bijective for the 16x16 grid)
  const int lin = blockIdx.y * gridDim.x + blockIdx.x;
  const int xcd = lin & 7, loc = lin >> 3;
  const int bxs = (xcd & 1) * 8 + (loc & 7);
  const int bys = (xcd >> 1) * 4 + (loc >> 3);
  const int m0 = bys * 256, n0 = bxs * 256;

  f32x4 acc[8][4] = {};

  auto stage = [&](int kk, int buf) {
    #pragma unroll
    for (int t = 0; t < 8; ++t) {
      int c0 = wv*64 + t*512;                   // wave-uniform base chunk
      int ch = c0 + lane;
      if (c0 < 2048) {
        int r = ch >> 3, j = (ch & 7) ^ (r & 7);
        async_cp16(&A[(size_t)(m0 + r)*768 + kk + j*8], &As[buf][(size_t)c0*8]);
      } else {
        int ch2 = ch - 2048, r = ch2 >> 3, j = (ch2 & 7) ^ (r & 7);
        async_cp16(&Bt[(size_t)(n0 + r)*768 + kk + j*8], &Bs[buf][(size_t)(c0 - 2048)*8]);
      }
    }
  };

  stage(0, 0);
  __syncthreads();

  #pragma unroll
  for (int t = 0; t < 12; ++t) {                // K = 768 = 12 x 64
    const int buf = t & 1;
    if (t + 1 < 12) stage((t + 1) * 64, buf ^ 1);

    const bf16* Asb = &As[buf][0];
    const bf16* Bsb = &Bs[buf][0];

    #pragma unroll
    for (int kc = 0; kc < 2; ++kc) {
      bf16x8 bfr[4];
      #pragma unroll
      for (int nt = 0; nt < 4; ++nt) {
        int rb = wc*64 + nt*16 + l16;
        int c  = (kc*4 + quad) ^ (rb & 7);
        bfr[nt] = *(const bf16x8*)&Bsb[rb*64 + c*8];
      }
      #pragma unroll
      for (int mt = 0; mt < 8; ++mt) {
        int ra = wr*128 + mt*16 + l16;
        int ca = (kc*4 + quad) ^ (ra & 7);
        bf16x8 af = *(const bf16x8*)&Asb[ra*64 + ca*8];
        #pragma unroll
        for (int nt = 0; nt < 4; ++nt)
          acc[mt][nt] = __builtin_amdgcn_mfma_f32_16x16x32_bf16(af, bfr[nt], acc[mt][nt], 0, 0, 0);
      }
    }
    if (t + 1 < 12) __syncthreads();
  }

  // GELU epilogue: cols interleave (a,g); even lane holds a, odd holds g
  #pragma unroll
  for (int mt = 0; mt < 8; ++mt) {
    #pragma unroll
    for (int nt = 0; nt < 4; ++nt) {
      int row = m0 + wr*128 + mt*16 + quad*4;
      int col = n0 + wc*64 + nt*16 + l16;
      #pragma unroll
      for (int r = 0; r < 4; ++r) {
        float v = acc[mt][nt][r];
        float g = __shfl_xor(v, 1);
        if (!(lane & 1)) {
          float ge = 0.5f * g * (1.f + erff(g * 0.70710678118654752f));
          Cb[(size_t)(row + r)*(N >> 1) + (col >> 1)] = __float2bfloat16(v * ge);
        }
      }
    }
  }
}

// ---------------------------------------------------------------------------
// LayerNorm (row = 768, f32 in, bf16 out) — used once for layer-0 attn-LN
// ---------------------------------------------------------------------------
__global__ __launch_bounds__(256) void ln_kernel(
    const float* __restrict__ x, const float* __restrict__ g,
    const float* __restrict__ bta, bf16* __restrict__ out)
{
  const int row = blockIdx.x, tid = threadIdx.x;
  const size_t base = (size_t)row * DIM;
  float v[3];
  #pragma unroll
  for (int j = 0; j < 3; ++j) v[j] = x[base + tid + j*256];
  float s  = v[0] + v[1] + v[2];
  float ss = v[0]*v[0] + v[1]*v[1] + v[2]*v[2];
  #pragma unroll
  for (int off = 32; off; off >>= 1) { s += __shfl_xor(s, off); ss += __shfl_xor(ss, off); }
  __shared__ float red[8];
  int w = tid >> 6;
  if ((tid & 63) == 0) { red[w] = s; red[w + 4] = ss; }
  __syncthreads();
  s  = red[0] + red[1] + red[2] + red[3];
  ss = red[4] + red[5] + red[6] + red[7];
  float mean = s * (1.f/768.f);
  float var  = ss * (1.f/768.f) - mean*mean;
  float rstd = rsqrtf(fmaxf(var, 0.f) + 1e-5f);
  #pragma unroll
  for (int j = 0; j < 3; ++j) {
    int c = tid + j*256;
    float bv = bta ? bta[c] : 0.f;
    out[base + c] = __float2bfloat16((v[j] - mean) * rstd * g[c] + bv);
  }
}

// ---------------------------------------------------------------------------
// Split-K reduce + residual + optional LN (fused). Row = 768.
// ---------------------------------------------------------------------------
__global__ __launch_bounds__(256) void redln_kernel(
    const float* __restrict__ P0, const float* __restrict__ P1,
    const float* __restrict__ res,
    float* __restrict__ xo32, bf16* __restrict__ xo16, float* __restrict__ outf,
    const float* __restrict__ g, const float* __restrict__ bta,
    bf16* __restrict__ lnout)
{
  const int row = blockIdx.x, tid = threadIdx.x;
  const size_t base = (size_t)row * DIM;
  float v[3];
  #pragma unroll
  for (int j = 0; j < 3; ++j) {
    size_t idx = base + tid + j*256;
    v[j] = res[idx] + P0[idx] + P1[idx];
    if (xo32) xo32[idx] = v[j];
    if (xo16) xo16[idx] = __float2bfloat16(v[j]);
    if (outf) outf[idx] = v[j];
  }
  if (!g) return;
  float s  = v[0] + v[1] + v[2];
  float ss = v[0]*v[0] + v[1]*v[1] + v[2]*v[2];
  #pragma unroll
  for (int off = 32; off; off >>= 1) { s += __shfl_xor(s, off); ss += __shfl_xor(ss, off); }
  __shared__ float red[8];
  int w = tid >> 6;
  if ((tid & 63) == 0) { red[w] = s; red[w + 4] = ss; }
  __syncthreads();
  s  = red[0] + red[1] + red[2] + red[3];
  ss = red[4] + red[5] + red[6] + red[7];
  float mean = s * (1.f/768.f);
  float var  = ss * (1.f/768.f) - mean*mean;
  float rstd = rsqrtf(fmaxf(var, 0.f) + 1e-5f);
  #pragma unroll
  for (int j = 0; j < 3; ++j) {
    int c = tid + j*256;
    float bv = bta ? bta[c] : 0.f;
    lnout[base + c] = __float2bfloat16((v[j] - mean) * rstd * g[c] + bv);
  }
}

// ---------------------------------------------------------------------------
// Flash attention, fixed softmax max (Cauchy-Schwarz bound; 8 folded into q).
// R10 structure + R13: Q-HOIST — Q is loop-invariant, so the per-wave Q
// fragment (8 VGPRs) is loaded ONCE directly from global (16B/lane at 128B
// row stride, L2-resident, no swizzle needed) instead of being staged to
// LDS and re-read (2 ds_read_b128 + lgkm waits) every one of 16 tiles.
// Qs LDS buffer deleted (49.2 -> 41 KB).
// ---------------------------------------------------------------------------
__global__ __launch_bounds__(256) void attn_kernel(
    const bf16* __restrict__ qh, const bf16* __restrict__ kh,
    const bf16* __restrict__ vt, const float* __restrict__ qsc,
    const float* __restrict__ ksc, bf16* __restrict__ ob)
{
  __shared__ __align__(16) bf16 Ks[2][64*64];
  __shared__ __align__(16) bf16 Vs[2][64*64];
  __shared__ __align__(16) bf16 Ps[4][16*72];

  const int tid = threadIdx.x;
  const int lane = tid & 63, w = tid >> 6;
  const int quad = lane >> 4, l16 = lane & 15;
  const int qt = blockIdx.x, bh = blockIdx.y;
  const int b = bh / HEADS, h = bh % HEADS;
  const size_t base = (size_t)bh * NN * DH;

  float mq = fabsf(qsc[lane]), mk = fabsf(ksc[lane]);
  #pragma unroll
  for (int off = 1; off < 64; off <<= 1) {
    mq = fmaxf(mq, __shfl_xor(mq, off));
    mk = fmaxf(mk, __shfl_xor(mk, off));
  }
  const float Mb = 8.f * mq * mk;

  // Q-hoist: wave w owns q-rows qt*64 + w*16 .. +15; lane reads its 16B
  // fragment once, straight from global.
  bf16x8 aq[2];
  const int rq = w*16 + l16;
  #pragma unroll
  for (int kc = 0; kc < 2; ++kc)
    aq[kc] = *(const bf16x8*)&qh[base + (size_t)(qt*64 + rq)*64 + kc*32 + quad*8];

  // stage one K/V tile (1024 chunks, 4/thread) into buffer buf
  auto stage_kv = [&](int kt0, int buf) {
    #pragma unroll
    for (int t = 0; t < 4; ++t) {
      int c0 = w*64 + t*256, ch = c0 + lane;
      if (c0 < 512) {            // K: rows = n, cols = dh
        int r = ch >> 3, jl = (ch & 7) ^ (r & 7);
        async_cp16(&kh[base + (size_t)(kt0*64 + r)*64 + jl*8],
                   &Ks[buf][(size_t)c0*8]);
      } else {                   // V: rows = dh, cols = n (vt is (b,h,dh,n))
        int ch2 = ch - 512, r = ch2 >> 3, jl = (ch2 & 7) ^ (r & 7);
        async_cp16(&vt[base + (size_t)r*NN + kt0*64 + jl*8],
                   &Vs[buf][(size_t)(c0 - 512)*8]);
      }
    }
  };

  f32x4 o[4] = {};
  float pl[4] = {0.f, 0.f, 0.f, 0.f};

  stage_kv(0, 0);
  __syncthreads();               // drains tile-0 loads

  for (int kt0 = 0; kt0 < NN/64; ++kt0) {
    const int buf = kt0 & 1;
    if (kt0 + 1 < NN/64) stage_kv(kt0 + 1, buf ^ 1);  // async, hides under MFMA

    f32x4 s[4] = {};
    __builtin_amdgcn_s_setprio(1);
    #pragma unroll
    for (int kt = 0; kt < 4; ++kt)
      #pragma unroll
      for (int kc = 0; kc < 2; ++kc) {
        int rb = kt*16 + l16;
        bf16x8 bk = *(const bf16x8*)&Ks[buf][rb*64 + ((kc*4 + quad) ^ (rb & 7))*8];
        s[kt] = __builtin_amdgcn_mfma_f32_16x16x32_bf16(aq[kc], bk, s[kt], 0, 0, 0);
      }
    __builtin_amdgcn_s_setprio(0);

    #pragma unroll
    for (int r = 0; r < 4; ++r) {
      #pragma unroll
      for (int kt = 0; kt < 4; ++kt) {
        float pv = __expf(s[kt][r] - Mb);
        pl[r] += pv;
        Ps[w][(quad*4 + r)*72 + kt*16 + l16] = __float2bfloat16(pv);
      }
    }
    // no barrier: Ps[w] is produced and consumed by the same wave.

    __builtin_amdgcn_s_setprio(1);
    #pragma unroll
    for (int kc = 0; kc < 2; ++kc) {
      bf16x8 ap = *(const bf16x8*)&Ps[w][l16*72 + kc*32 + quad*8];
      #pragma unroll
      for (int nt = 0; nt < 4; ++nt) {
        int rv = nt*16 + l16;
        bf16x8 bv = *(const bf16x8*)&Vs[buf][rv*64 + ((kc*4 + quad) ^ (rv & 7))*8];
        o[nt] = __builtin_amdgcn_mfma_f32_16x16x32_bf16(ap, bv, o[nt], 0, 0, 0);
      }
    }
    __builtin_amdgcn_s_setprio(0);

    if (kt0 + 1 < NN/64) __syncthreads();
  }

  float l[4];
  #pragma unroll
  for (int r = 0; r < 4; ++r) {
    float rs = pl[r];
    #pragma unroll
    for (int off = 1; off < 16; off <<= 1) rs += __shfl_xor(rs, off);
    l[r] = rs;
  }

  #pragma unroll
  for (int nt = 0; nt < 4; ++nt)
    #pragma unroll
    for (int r = 0; r < 4; ++r) {
      int n = qt*64 + w*16 + quad*4 + r;
      int dcol = nt*16 + l16;
      ob[((size_t)(b*NN + n)*HEADS + h)*DH + dcol] = __float2bfloat16(o[nt][r] / l[r]);
    }
}

// ---------------------------------------------------------------------------
// f32 -> bf16 cast (vectorized x8)
// ---------------------------------------------------------------------------
__global__ __launch_bounds__(256) void cast_kernel(
    const float* __restrict__ x, bf16* __restrict__ o)
{
  size_t i = ((size_t)blockIdx.x*256 + threadIdx.x) * 8;
  float4 f0 = *(const float4*)(x + i);
  float4 f1 = *(const float4*)(x + i + 4);
  union { uint4 u; bf16 h[8]; } p;
  p.h[0] = __float2bfloat16(f0.x); p.h[1] = __float2bfloat16(f0.y);
  p.h[2] = __float2bfloat16(f0.z); p.h[3] = __float2bfloat16(f0.w);
  p.h[4] = __float2bfloat16(f1.x); p.h[5] = __float2bfloat16(f1.y);
  p.h[6] = __float2bfloat16(f1.z); p.h[7] = __float2bfloat16(f1.w);
  *(uint4*)(o + i) = p.u;
}

// ---------------------------------------------------------------------------
// Fused weight transpose: 5 weights f32 (RxC) -> bf16 (CxR), one dispatch.
// perm=1 (wff1): output rows interleave a/g columns.
// ---------------------------------------------------------------------------
struct TD { const float* src; bf16* dst; int R, C, base, perm; };
struct TDs5 { TD d[5]; };

__global__ __launch_bounds__(256) void wtrans_kernel(TDs5 a)
{
  const int blk = blockIdx.x;
  int di = 0;
  #pragma unroll
  for (int k = 1; k < 5; ++k) if (blk >= a.d[k].base) di = k;
  const TD d = a.d[di];
  const int local = blk - d.base;
  const int tilesX = d.C >> 5;
  const int by = local / tilesX, bx = local - by*tilesX;
  __shared__ float t[32][33];
  const int tx = threadIdx.x & 31, ty = threadIdx.x >> 5;
  const int c0 = bx*32, r0 = by*32;
  #pragma unroll
  for (int i = 0; i < 4; ++i)
    t[ty + i*8][tx] = d.src[(size_t)(r0 + ty + i*8)*d.C + c0 + tx];
  __syncthreads();
  const int half = d.C >> 1;
  #pragma unroll
  for (int i = 0; i < 4; ++i) {
    int c = c0 + ty + i*8;
    int rout = d.perm ? ((c < half) ? 2*c : 2*(c - half) + 1) : c;
    d.dst[(size_t)rout*d.R + r0 + tx] = __float2bfloat16(t[tx][ty + i*8]);
  }
}

// ---------------------------------------------------------------------------
extern "C" void kernel_launch(void* const* d_in, const int* in_sizes, int n_in,
                              void* d_out, int out_size, void* d_ws, size_t ws_size,
                              hipStream_t stream)
{
  const float* x_in       = (const float*)d_in[0];
  const float* attn_gamma = (const float*)d_in[1];
  const float* wq         = (const float*)d_in[2];
  const float* wkv        = (const float*)d_in[3];
  const float* q_scale    = (const float*)d_in[4];
  const float* k_scale    = (const float*)d_in[5];
  const float* wo         = (const float*)d_in[6];
  const float* ff_gamma   = (const float*)d_in[7];
  const float* ff_beta    = (const float*)d_in[8];
  const float* wff1       = (const float*)d_in[9];
  const float* wff2       = (const float*)d_in[10];
  float* outp = (float*)d_out;
  char* ws = (char*)d_ws;

  const size_t E = (size_t)ROWS * DIM;      // 3,145,728 elems
  float* xw32 = (float*)ws;                     // [0, 12.58M) f32 residual
  bf16*  xw16 = (bf16*)(ws + 12582912);         // bf16 shadow (kv input)
  bf16*  S_h  = (bf16*)(ws + 18874368);         // LN out / attn out
  char*  BIGb = ws + 25165824;                  // 37.75M scratch
  bf16*  WT   = (bf16*)(ws + 62914560);         // transposed weights
  bf16*  qbuf  = (bf16*)BIGb;                   // (dead: rope fused) E elems
  bf16*  qhb   = qbuf + 2*E;                    // E
  bf16*  khb   = qbuf + 3*E;                    // E
  bf16*  vtb   = qbuf + 4*E;                    // E
  bf16*  glbuf = (bf16*)BIGb;                   // ROWS*FFI (q..vt dead by then)
  float* wP    = (float*)BIGb;                  // wo partials 2E f32
  float* fP    = (float*)(BIGb + 16777216);     // ff2 partials 2E f32 (tail
                                                //   spills into dead wqT..woT,
                                                //   rebuilt next layer)
  bf16*  wqT   = WT;                            // [768][768]
  bf16*  wkvT  = WT + 589824;                   // [1536][768]
  bf16*  woT   = WT + 1769472;                  // [768][768]
  bf16*  wff1T = WT + 2359296;                  // [4096][768] (interleaved a/g)
  bf16*  wff2T = WT + 5505024;                  // [768][2048]

  // RoPE table: after WT if workspace allows (built once), else in BIGb
  // (clobbered by wP each layer -> rebuilt per layer).
  const size_t rtab_off = 77070336;             // WT end
  const bool tonce = ws_size >= rtab_off + 262144;
  float* rtab = tonce ? (float*)(ws + rtab_off) : (float*)BIGb;

  cast_kernel<<<1536, 256, 0, stream>>>(x_in, xw16);
  ln_kernel<<<ROWS, 256, 0, stream>>>(x_in, attn_gamma, nullptr, S_h);
  if (tonce) ropetab_kernel<<<128, 256, 0, stream>>>(rtab);

  for (int i = 0; i < NDEPTH; ++i) {
    const float* xsrc = (i == 0) ? x_in : xw32;

    TDs5 td;
    td.d[0] = { wq   + (size_t)i*589824,  wqT,   768,  768,    0, 0 };
    td.d[1] = { wkv  + (size_t)i*1179648, wkvT,  768, 1536,  576, 0 };
    td.d[2] = { wo   + (size_t)i*589824,  woT,   768,  768, 1728, 0 };
    td.d[3] = { wff1 + (size_t)i*3145728, wff1T, 768, 4096, 2304, 1 };
    td.d[4] = { wff2 + (size_t)i*1572864, wff2T, 2048, 768, 5376, 0 };
    wtrans_kernel<<<6912, 256, 0, stream>>>(td);
    if (!tonce) ropetab_kernel<<<128, 256, 0, stream>>>(rtab);

    // q/k: GEMM + fused rope+l2norm+scale -> qhb/khb ; v transposed -> vtb
    qkv_kernel<<<dim3(12,32,2), 256, 0, stream>>>(S_h, xw16, wqT, wkvT, rtab,
                                                  q_scale + i*DH, k_scale + i*DH,
                                                  qhb, khb, vtb);
    attn_kernel<<<dim3(16,48), 256, 0, stream>>>(qhb, khb, vtb,
                                                 q_scale + i*DH, k_scale + i*DH, S_h);
    // x = x + o @ wo (split-K=2) ; fused reduce + residual + ff-LN
    gemm_splitk_kernel<64,384,768><<<dim3(12,32,2), 256, 0, stream>>>(S_h, woT, wP, ROWS, DIM);
    redln_kernel<<<ROWS, 256, 0, stream>>>(wP, wP + E, xsrc, xw32, nullptr, nullptr,
                                           ff_gamma + i*DIM, ff_beta + i*DIM, S_h);
    // gl = a*gelu(g) fused in FF1 epilogue (256^2 2-phase kernel)
    gemm256_kernel<<<dim3(16,16), 512, 0, stream>>>(S_h, wff1T, glbuf, ROWS, 2*FFI);
    // x = x + gl @ wff2 (split-K=2) ; fused reduce + residual (+ next attn-LN)
    gemm_splitk_kernel<64,1024,2048><<<dim3(12,32,2), 256, 0, stream>>>(glbuf, wff2T, fP, ROWS, DIM);
    if (i < NDEPTH-1)
      redln_kernel<<<ROWS, 256, 0, stream>>>(fP, fP + E, xw32, xw32, xw16, nullptr,
                                             attn_gamma + (i+1)*DIM, nullptr, S_h);
    else
      redln_kernel<<<ROWS, 256, 0, stream>>>(fP, fP + E, xw32, nullptr, nullptr, outp,
                                             nullptr, nullptr, nullptr);
  }
}

// Round 14
// 866.658 us; speedup vs baseline: 1.0515x; 1.0076x over previous
//
#include <hip/hip_runtime.h>
#include <hip/hip_bf16.h>
#include <math.h>

typedef __hip_bfloat16 bf16;
typedef __bf16 bf16x8 __attribute__((ext_vector_type(8)));
typedef float f32x4 __attribute__((ext_vector_type(4)));

#define NDEPTH 4
#define DIM 768
#define HEADS 12
#define DH 64
#define INNER 768
#define FFI 2048
#define BB 4
#define NN 1024
#define ROWS (BB*NN)   // 4096

__device__ __forceinline__ void async_cp16(const bf16* g, bf16* l) {
  __builtin_amdgcn_global_load_lds(
      (const __attribute__((address_space(1))) unsigned int*)g,
      (__attribute__((address_space(3))) unsigned int*)l, 16, 0, 0);
}

// ---------------------------------------------------------------------------
// bf16 MFMA GEMM body (R1 config — measured best for the N<=1536 GEMMs).
// C[MxN] = A[MxK] @ Bt[NxK]^T. 128xBN tile, BK=64, 4 waves, XOR-swizzled LDS
// (0 bank conflicts measured). 2-phase double-buffered pipeline.
// GEMM-plateau history: 6 structural variants (R2,R3,R4,R5,R7/R8) all
// null/negative -> ~500 TF is this small-K regime's plateau; strategy since
// R9 = remove work, not schedule.
// R12: QROPE / VOUT-K epilogues fuse RoPE + head-L2-norm + per-dim scale
// directly into the GEMM output (killed rope_kernel + qbuf/kbuf round trip,
// ~25 MB/layer; measured -30us total). Requires WN==64 (wave col span ==
// one head) so the norm is a within-wave shfl reduction.
// rtab: precomputed (cos,sin) table [n][32 pairs], f32.
// ---------------------------------------------------------------------------
template<int BN, bool GELU, bool VOUT, bool QROPE, int K, int LD>
__device__ __forceinline__ void gemm_body(
    const bf16* __restrict__ A, const bf16* __restrict__ Bt,
    bf16* __restrict__ Cb, float* __restrict__ Cf, const float* __restrict__ Rf,
    bf16* __restrict__ Vt, const float* __restrict__ rtab,
    const float* __restrict__ sc, bf16* __restrict__ Hout,
    int M, int N, int bx, int by, bf16* As, bf16* Bs)
{
  constexpr int WN = BN / 2;      // wave col extent
  constexpr int NT = WN / 16;     // col MFMA tiles per wave
  static_assert(WN == 64 || !(QROPE || VOUT), "rope/V epilogue needs WN==64");
  const int tid  = threadIdx.x;
  const int lane = tid & 63, w = tid >> 6;
  const int quad = lane >> 4, l16 = lane & 15;
  const int wr = w >> 1, wc = w & 1;
  const int m0 = by * 128, n0 = bx * BN;

  f32x4 acc[4][NT] = {};

  constexpr int CHA = 128 * 8;    // A chunks (8 x 16B per 64-elem row)
  constexpr int CH  = CHA + BN * 8;
  constexpr int NCH = CH / 256;   // chunks per thread
  constexpr int NTK = K / 64;     // K-steps

  auto stage = [&](int kk, int buf) {
    bf16* Asb = As + buf * (128*64);
    bf16* Bsb = Bs + buf * (BN*64);
    #pragma unroll
    for (int t = 0; t < NCH; ++t) {
      int c0 = w*64 + t*256;      // wave-uniform LDS base chunk
      int ch = c0 + lane;
      if (c0 < CHA) {
        int r = ch >> 3, j = (ch & 7) ^ (r & 7);
        async_cp16(&A[(size_t)(m0 + r)*LD + kk + j*8], &Asb[(size_t)c0*8]);
      } else {
        int ch2 = ch - CHA, r = ch2 >> 3, j = (ch2 & 7) ^ (r & 7);
        async_cp16(&Bt[(size_t)(n0 + r)*LD + kk + j*8], &Bsb[(size_t)(c0 - CHA)*8]);
      }
    }
  };

  stage(0, 0);
  __syncthreads();   // vmcnt(0) drain + barrier

  #pragma unroll
  for (int t = 0; t < NTK; ++t) {
    const int buf = t & 1;
    if (t + 1 < NTK) stage((t + 1) * 64, buf ^ 1);

    const bf16* Asb = As + buf * (128*64);
    const bf16* Bsb = Bs + buf * (BN*64);

    #pragma unroll
    for (int kc = 0; kc < 2; ++kc) {
      bf16x8 bfr[NT];
      #pragma unroll
      for (int nt = 0; nt < NT; ++nt) {
        int rb = wc*WN + nt*16 + l16;
        int c  = (kc*4 + quad) ^ (rb & 7);
        bfr[nt] = *(const bf16x8*)&Bsb[rb*64 + c*8];
      }
      #pragma unroll
      for (int mt = 0; mt < 4; ++mt) {
        int ra = wr*64 + mt*16 + l16;
        int ca = (kc*4 + quad) ^ (ra & 7);
        bf16x8 af = *(const bf16x8*)&Asb[ra*64 + ca*8];
        #pragma unroll
        for (int nt = 0; nt < NT; ++nt)
          acc[mt][nt] = __builtin_amdgcn_mfma_f32_16x16x32_bf16(af, bfr[nt], acc[mt][nt], 0, 0, 0);
      }
    }
    if (t + 1 < NTK) __syncthreads();
  }

  if constexpr (QROPE || VOUT) {
    const int cw = n0 + wc*64;                 // wave col base (one head span)
    if (QROPE || cw < INNER) {
      // --- rope + head-L2-norm + per-dim scale -> Hout (b,h,n,dh) ---
      const int hh = cw >> 6;
      const float S = QROPE ? 8.f : 1.f;       // ATTN_SCALE folded into q
      float scd[NT];
      #pragma unroll
      for (int nt = 0; nt < NT; ++nt) scd[nt] = sc[nt*16 + l16];
      #pragma unroll
      for (int mt = 0; mt < 4; ++mt) {
        float rot[NT][4];
        float ns[4] = {0.f, 0.f, 0.f, 0.f};
        #pragma unroll
        for (int nt = 0; nt < NT; ++nt) {
          int d = nt*16 + l16;
          #pragma unroll
          for (int r = 0; r < 4; ++r) {
            float v = acc[mt][nt][r];
            float p = __shfl_xor(v, 1);        // pair partner (d ^ 1)
            int row = m0 + wr*64 + mt*16 + quad*4 + r;
            int n = row & 1023;
            float2 cssn = ((const float2*)rtab)[n*32 + (d >> 1)];
            // even d: re*c - im*s ; odd d: re*s + im*c
            float rv = (l16 & 1) ? (p*cssn.y + v*cssn.x)
                                 : (v*cssn.x - p*cssn.y);
            rot[nt][r] = rv;
            ns[r] += rv*rv;
          }
        }
        #pragma unroll
        for (int r = 0; r < 4; ++r) {
          float s2 = ns[r];
          #pragma unroll
          for (int off = 1; off < 16; off <<= 1) s2 += __shfl_xor(s2, off);
          ns[r] = S / fmaxf(sqrtf(s2), 1e-12f);
        }
        #pragma unroll
        for (int nt = 0; nt < NT; ++nt) {
          int d = nt*16 + l16;
          #pragma unroll
          for (int r = 0; r < 4; ++r) {
            int row = m0 + wr*64 + mt*16 + quad*4 + r;
            int b = row >> 10, n = row & 1023;
            Hout[(((size_t)b*HEADS + hh)*NN + n)*DH + d] =
                __float2bfloat16(rot[nt][r] * ns[r] * scd[nt]);
          }
        }
      }
    } else {
      // --- V half -> (b,h,dh,n) packed 8B (unchanged) ---
      #pragma unroll
      for (int mt = 0; mt < 4; ++mt) {
        #pragma unroll
        for (int nt = 0; nt < NT; ++nt) {
          int row = m0 + wr*64 + mt*16 + quad*4;
          int col = n0 + wc*64 + nt*16 + l16;
          int c2 = col - INNER, hh2 = c2 >> 6, d = c2 & 63;
          int b = row >> 10, nn = row & 1023;
          union { ushort4 u4; bf16 h4[4]; } p;
          #pragma unroll
          for (int r = 0; r < 4; ++r) p.h4[r] = __float2bfloat16(acc[mt][nt][r]);
          *(ushort4*)&Vt[(((size_t)b*HEADS + hh2)*DH + d)*NN + nn] = p.u4;
        }
      }
    }
  } else {
    #pragma unroll
    for (int mt = 0; mt < 4; ++mt) {
      #pragma unroll
      for (int nt = 0; nt < NT; ++nt) {
        int row = m0 + wr*64 + mt*16 + quad*4;
        int col = n0 + wc*WN + nt*16 + l16;
        if (GELU) {
          #pragma unroll
          for (int r = 0; r < 4; ++r) {
            float v = acc[mt][nt][r];
            float g = __shfl_xor(v, 1);          // even lane: v=a, g from odd
            if (!(lane & 1)) {
              float ge = 0.5f * g * (1.f + erff(g * 0.70710678118654752f));
              Cb[(size_t)(row + r)*(N >> 1) + (col >> 1)] = __float2bfloat16(v * ge);
            }
          }
        } else {
          #pragma unroll
          for (int r = 0; r < 4; ++r) {
            float v = acc[mt][nt][r];
            size_t idx = (size_t)(row + r) * N + col;
            if (Rf) v += Rf[idx];
            if (Cf) Cf[idx] = v;
            if (Cb) Cb[idx] = __float2bfloat16(v);
          }
        }
      }
    }
  }
}

// Split-K=2: z selects K-half; partials to P[z*M*N]
template<int BN, int KH, int LD>
__global__ __launch_bounds__(256) void gemm_splitk_kernel(
    const bf16* __restrict__ A, const bf16* __restrict__ Bt,
    float* __restrict__ P, int M, int N)
{
  __shared__ __align__(16) bf16 As[2*128*64];
  __shared__ __align__(16) bf16 Bs[2*BN*64];
  const int z = blockIdx.z;
  gemm_body<BN,false,false,false,KH,LD>(A + (size_t)z*KH, Bt + (size_t)z*KH, nullptr,
                                        P + (size_t)z*M*N, nullptr, nullptr,
                                        nullptr, nullptr, nullptr,
                                        M, N, blockIdx.x, blockIdx.y, As, Bs);
}

// combined grid 18x32: bx<6 -> q = LN(x) @ wq with fused rope->qhb;
// bx>=6 -> kv = x @ wkv (K-half fused rope->khb, V-half transposed->vt)
__global__ __launch_bounds__(256) void qkv_kernel(
    const bf16* __restrict__ h, const bf16* __restrict__ x16,
    const bf16* __restrict__ wqT, const bf16* __restrict__ wkvT,
    const float* __restrict__ rtab,
    const float* __restrict__ qsc, const float* __restrict__ ksc,
    bf16* __restrict__ qh, bf16* __restrict__ kh, bf16* __restrict__ vt)
{
  __shared__ __align__(16) bf16 As[2*128*64];
  __shared__ __align__(16) bf16 Bs[2*128*64];
  if (blockIdx.x < 6) {
    gemm_body<128,false,false,true,768,768>(h, wqT, nullptr, nullptr, nullptr,
                                            nullptr, rtab, qsc, qh,
                                            ROWS, INNER, blockIdx.x, blockIdx.y, As, Bs);
  } else {
    gemm_body<128,false,true,false,768,768>(x16, wkvT, nullptr, nullptr, nullptr,
                                            vt, rtab, ksc, kh,
                                            ROWS, 2*INNER, blockIdx.x - 6, blockIdx.y, As, Bs);
  }
}

// ---------------------------------------------------------------------------
// RoPE cos/sin table: tab[n][pr] = (cos, sin) of angle(n, pr), 1024 x 32 f32x2
// ---------------------------------------------------------------------------
__global__ __launch_bounds__(256) void ropetab_kernel(float* __restrict__ tab)
{
  int idx = blockIdx.x*256 + threadIdx.x;   // 32768 entries
  int n = idx >> 5, pr = idx & 31;
  float xp = (float)(n & 31), yp = (float)((n >> 5) & 31);
  int t = pr >> 1;
  float freq = powf(10000.f, -(float)t / 16.f);
  float ang = (pr & 1) ? yp * freq : xp * freq;
  float sn, cs;
  sincosf(ang, &sn, &cs);
  ((float2*)tab)[idx] = make_float2(cs, sn);
}

// ---------------------------------------------------------------------------
// 256x256 8-wave GEMM + GELU for FF1 (M=N=4096, K=768). R6 2-PHASE form
// (measured 50.0us — best). 2D-region XCD swizzle kept (FETCH 28->19MB).
// ---------------------------------------------------------------------------
__global__ __launch_bounds__(512) void gemm256_kernel(
    const bf16* __restrict__ A, const bf16* __restrict__ Bt,
    bf16* __restrict__ Cb, int M, int N)
{
  __shared__ __align__(16) bf16 As[2][256*64];
  __shared__ __align__(16) bf16 Bs[2][256*64];

  const int tid  = threadIdx.x;
  const int lane = tid & 63, wv = tid >> 6;
  const int quad = lane >> 4, l16 = lane & 15;
  const int wr = wv >> 2, wc = wv & 3;          // 2 x 4 wave grid

  // 2D-region XCD swizzle (bijective for the 16x16 grid)
  const int lin = blockIdx.y * gridDim.x + blockIdx.x;
  const int xcd = lin & 7, loc = lin >> 3;
  const int bxs = (xcd & 1) * 8 + (loc & 7);
  const int bys = (xcd >> 1) * 4 + (loc >> 3);
  const int m0 = bys * 256, n0 = bxs * 256;

  f32x4 acc[8][4] = {};

  auto stage = [&](int kk, int buf) {
    #pragma unroll
    for (int t = 0; t < 8; ++t) {
      int c0 = wv*64 + t*512;                   // wave-uniform base chunk
      int ch = c0 + lane;
      if (c0 < 2048) {
        int r = ch >> 3, j = (ch & 7) ^ (r & 7);
        async_cp16(&A[(size_t)(m0 + r)*768 + kk + j*8], &As[buf][(size_t)c0*8]);
      } else {
        int ch2 = ch - 2048, r = ch2 >> 3, j = (ch2 & 7) ^ (r & 7);
        async_cp16(&Bt[(size_t)(n0 + r)*768 + kk + j*8], &Bs[buf][(size_t)(c0 - 2048)*8]);
      }
    }
  };

  stage(0, 0);
  __syncthreads();

  #pragma unroll
  for (int t = 0; t < 12; ++t) {                // K = 768 = 12 x 64
    const int buf = t & 1;
    if (t + 1 < 12) stage((t + 1) * 64, buf ^ 1);

    const bf16* Asb = &As[buf][0];
    const bf16* Bsb = &Bs[buf][0];

    #pragma unroll
    for (int kc = 0; kc < 2; ++kc) {
      bf16x8 bfr[4];
      #pragma unroll
      for (int nt = 0; nt < 4; ++nt) {
        int rb = wc*64 + nt*16 + l16;
        int c  = (kc*4 + quad) ^ (rb & 7);
        bfr[nt] = *(const bf16x8*)&Bsb[rb*64 + c*8];
      }
      #pragma unroll
      for (int mt = 0; mt < 8; ++mt) {
        int ra = wr*128 + mt*16 + l16;
        int ca = (kc*4 + quad) ^ (ra & 7);
        bf16x8 af = *(const bf16x8*)&Asb[ra*64 + ca*8];
        #pragma unroll
        for (int nt = 0; nt < 4; ++nt)
          acc[mt][nt] = __builtin_amdgcn_mfma_f32_16x16x32_bf16(af, bfr[nt], acc[mt][nt], 0, 0, 0);
      }
    }
    if (t + 1 < 12) __syncthreads();
  }

  // GELU epilogue: cols interleave (a,g); even lane holds a, odd holds g
  #pragma unroll
  for (int mt = 0; mt < 8; ++mt) {
    #pragma unroll
    for (int nt = 0; nt < 4; ++nt) {
      int row = m0 + wr*128 + mt*16 + quad*4;
      int col = n0 + wc*64 + nt*16 + l16;
      #pragma unroll
      for (int r = 0; r < 4; ++r) {
        float v = acc[mt][nt][r];
        float g = __shfl_xor(v, 1);
        if (!(lane & 1)) {
          float ge = 0.5f * g * (1.f + erff(g * 0.70710678118654752f));
          Cb[(size_t)(row + r)*(N >> 1) + (col >> 1)] = __float2bfloat16(v * ge);
        }
      }
    }
  }
}

// ---------------------------------------------------------------------------
// LayerNorm (row = 768, f32 in, bf16 out) — used once for layer-0 attn-LN
// ---------------------------------------------------------------------------
__global__ __launch_bounds__(256) void ln_kernel(
    const float* __restrict__ x, const float* __restrict__ g,
    const float* __restrict__ bta, bf16* __restrict__ out)
{
  const int row = blockIdx.x, tid = threadIdx.x;
  const size_t base = (size_t)row * DIM;
  float v[3];
  #pragma unroll
  for (int j = 0; j < 3; ++j) v[j] = x[base + tid + j*256];
  float s  = v[0] + v[1] + v[2];
  float ss = v[0]*v[0] + v[1]*v[1] + v[2]*v[2];
  #pragma unroll
  for (int off = 32; off; off >>= 1) { s += __shfl_xor(s, off); ss += __shfl_xor(ss, off); }
  __shared__ float red[8];
  int w = tid >> 6;
  if ((tid & 63) == 0) { red[w] = s; red[w + 4] = ss; }
  __syncthreads();
  s  = red[0] + red[1] + red[2] + red[3];
  ss = red[4] + red[5] + red[6] + red[7];
  float mean = s * (1.f/768.f);
  float var  = ss * (1.f/768.f) - mean*mean;
  float rstd = rsqrtf(fmaxf(var, 0.f) + 1e-5f);
  #pragma unroll
  for (int j = 0; j < 3; ++j) {
    int c = tid + j*256;
    float bv = bta ? bta[c] : 0.f;
    out[base + c] = __float2bfloat16((v[j] - mean) * rstd * g[c] + bv);
  }
}

// ---------------------------------------------------------------------------
// Split-K reduce + residual + optional LN (fused). Row = 768.
// R14: WAVE-PER-ROW layout — 768 f32 = 64 lanes x 3 float4, so one wave
// owns one row: 16B/lane contiguous loads (each instruction spans a
// contiguous 1KB), reduction is a pure 6-step shfl_xor wave reduce (no LDS,
// no __syncthreads). Block = 4 waves = 4 rows; grid = ROWS/4.
// (Old form: 4B scalar loads + LDS cross-wave reduce — ran ~3.5 TB/s.)
// ---------------------------------------------------------------------------
__global__ __launch_bounds__(256) void redln_kernel(
    const float* __restrict__ P0, const float* __restrict__ P1,
    const float* __restrict__ res,
    float* __restrict__ xo32, bf16* __restrict__ xo16, float* __restrict__ outf,
    const float* __restrict__ g, const float* __restrict__ bta,
    bf16* __restrict__ lnout)
{
  const int w = threadIdx.x >> 6, lane = threadIdx.x & 63;
  const int row = blockIdx.x * 4 + w;
  const size_t base = (size_t)row * DIM;

  float4 v4[3];
  float s = 0.f, ss = 0.f;
  #pragma unroll
  for (int j = 0; j < 3; ++j) {
    const int c = lane*4 + j*256;
    float4 a = *(const float4*)&P0[base + c];
    float4 b = *(const float4*)&P1[base + c];
    float4 rr = *(const float4*)&res[base + c];
    float4 t;
    t.x = rr.x + a.x + b.x; t.y = rr.y + a.y + b.y;
    t.z = rr.z + a.z + b.z; t.w = rr.w + a.w + b.w;
    v4[j] = t;
    if (xo32) *(float4*)&xo32[base + c] = t;
    if (outf) *(float4*)&outf[base + c] = t;
    if (xo16) {
      union { ushort4 u4; bf16 h4[4]; } p;
      p.h4[0] = __float2bfloat16(t.x); p.h4[1] = __float2bfloat16(t.y);
      p.h4[2] = __float2bfloat16(t.z); p.h4[3] = __float2bfloat16(t.w);
      *(ushort4*)&xo16[base + c] = p.u4;
    }
    s  += t.x + t.y + t.z + t.w;
    ss += t.x*t.x + t.y*t.y + t.z*t.z + t.w*t.w;
  }
  if (!g) return;
  #pragma unroll
  for (int off = 32; off; off >>= 1) { s += __shfl_xor(s, off); ss += __shfl_xor(ss, off); }
  float mean = s * (1.f/768.f);
  float var  = ss * (1.f/768.f) - mean*mean;
  float rstd = rsqrtf(fmaxf(var, 0.f) + 1e-5f);
  #pragma unroll
  for (int j = 0; j < 3; ++j) {
    const int c = lane*4 + j*256;
    float4 gv = *(const float4*)&g[c];
    float4 bv = bta ? *(const float4*)&bta[c] : make_float4(0.f,0.f,0.f,0.f);
    float4 t = v4[j];
    union { ushort4 u4; bf16 h4[4]; } p;
    p.h4[0] = __float2bfloat16((t.x - mean)*rstd*gv.x + bv.x);
    p.h4[1] = __float2bfloat16((t.y - mean)*rstd*gv.y + bv.y);
    p.h4[2] = __float2bfloat16((t.z - mean)*rstd*gv.z + bv.z);
    p.h4[3] = __float2bfloat16((t.w - mean)*rstd*gv.w + bv.w);
    *(ushort4*)&lnout[base + c] = p.u4;
  }
}

// ---------------------------------------------------------------------------
// Flash attention, fixed softmax max (Cauchy-Schwarz bound; 8 folded into q).
// R10 structure + R13 Q-hoist (Q fragment loaded once from global; no Qs).
// ---------------------------------------------------------------------------
__global__ __launch_bounds__(256) void attn_kernel(
    const bf16* __restrict__ qh, const bf16* __restrict__ kh,
    const bf16* __restrict__ vt, const float* __restrict__ qsc,
    const float* __restrict__ ksc, bf16* __restrict__ ob)
{
  __shared__ __align__(16) bf16 Ks[2][64*64];
  __shared__ __align__(16) bf16 Vs[2][64*64];
  __shared__ __align__(16) bf16 Ps[4][16*72];

  const int tid = threadIdx.x;
  const int lane = tid & 63, w = tid >> 6;
  const int quad = lane >> 4, l16 = lane & 15;
  const int qt = blockIdx.x, bh = blockIdx.y;
  const int b = bh / HEADS, h = bh % HEADS;
  const size_t base = (size_t)bh * NN * DH;

  float mq = fabsf(qsc[lane]), mk = fabsf(ksc[lane]);
  #pragma unroll
  for (int off = 1; off < 64; off <<= 1) {
    mq = fmaxf(mq, __shfl_xor(mq, off));
    mk = fmaxf(mk, __shfl_xor(mk, off));
  }
  const float Mb = 8.f * mq * mk;

  // Q-hoist: wave w owns q-rows qt*64 + w*16 .. +15; lane reads its 16B
  // fragment once, straight from global.
  bf16x8 aq[2];
  const int rq = w*16 + l16;
  #pragma unroll
  for (int kc = 0; kc < 2; ++kc)
    aq[kc] = *(const bf16x8*)&qh[base + (size_t)(qt*64 + rq)*64 + kc*32 + quad*8];

  // stage one K/V tile (1024 chunks, 4/thread) into buffer buf
  auto stage_kv = [&](int kt0, int buf) {
    #pragma unroll
    for (int t = 0; t < 4; ++t) {
      int c0 = w*64 + t*256, ch = c0 + lane;
      if (c0 < 512) {            // K: rows = n, cols = dh
        int r = ch >> 3, jl = (ch & 7) ^ (r & 7);
        async_cp16(&kh[base + (size_t)(kt0*64 + r)*64 + jl*8],
                   &Ks[buf][(size_t)c0*8]);
      } else {                   // V: rows = dh, cols = n (vt is (b,h,dh,n))
        int ch2 = ch - 512, r = ch2 >> 3, jl = (ch2 & 7) ^ (r & 7);
        async_cp16(&vt[base + (size_t)r*NN + kt0*64 + jl*8],
                   &Vs[buf][(size_t)(c0 - 512)*8]);
      }
    }
  };

  f32x4 o[4] = {};
  float pl[4] = {0.f, 0.f, 0.f, 0.f};

  stage_kv(0, 0);
  __syncthreads();               // drains tile-0 loads

  for (int kt0 = 0; kt0 < NN/64; ++kt0) {
    const int buf = kt0 & 1;
    if (kt0 + 1 < NN/64) stage_kv(kt0 + 1, buf ^ 1);  // async, hides under MFMA

    f32x4 s[4] = {};
    __builtin_amdgcn_s_setprio(1);
    #pragma unroll
    for (int kt = 0; kt < 4; ++kt)
      #pragma unroll
      for (int kc = 0; kc < 2; ++kc) {
        int rb = kt*16 + l16;
        bf16x8 bk = *(const bf16x8*)&Ks[buf][rb*64 + ((kc*4 + quad) ^ (rb & 7))*8];
        s[kt] = __builtin_amdgcn_mfma_f32_16x16x32_bf16(aq[kc], bk, s[kt], 0, 0, 0);
      }
    __builtin_amdgcn_s_setprio(0);

    #pragma unroll
    for (int r = 0; r < 4; ++r) {
      #pragma unroll
      for (int kt = 0; kt < 4; ++kt) {
        float pv = __expf(s[kt][r] - Mb);
        pl[r] += pv;
        Ps[w][(quad*4 + r)*72 + kt*16 + l16] = __float2bfloat16(pv);
      }
    }
    // no barrier: Ps[w] is produced and consumed by the same wave.

    __builtin_amdgcn_s_setprio(1);
    #pragma unroll
    for (int kc = 0; kc < 2; ++kc) {
      bf16x8 ap = *(const bf16x8*)&Ps[w][l16*72 + kc*32 + quad*8];
      #pragma unroll
      for (int nt = 0; nt < 4; ++nt) {
        int rv = nt*16 + l16;
        bf16x8 bv = *(const bf16x8*)&Vs[buf][rv*64 + ((kc*4 + quad) ^ (rv & 7))*8];
        o[nt] = __builtin_amdgcn_mfma_f32_16x16x32_bf16(ap, bv, o[nt], 0, 0, 0);
      }
    }
    __builtin_amdgcn_s_setprio(0);

    if (kt0 + 1 < NN/64) __syncthreads();
  }

  float l[4];
  #pragma unroll
  for (int r = 0; r < 4; ++r) {
    float rs = pl[r];
    #pragma unroll
    for (int off = 1; off < 16; off <<= 1) rs += __shfl_xor(rs, off);
    l[r] = rs;
  }

  #pragma unroll
  for (int nt = 0; nt < 4; ++nt)
    #pragma unroll
    for (int r = 0; r < 4; ++r) {
      int n = qt*64 + w*16 + quad*4 + r;
      int dcol = nt*16 + l16;
      ob[((size_t)(b*NN + n)*HEADS + h)*DH + dcol] = __float2bfloat16(o[nt][r] / l[r]);
    }
}

// ---------------------------------------------------------------------------
// f32 -> bf16 cast (vectorized x8)
// ---------------------------------------------------------------------------
__global__ __launch_bounds__(256) void cast_kernel(
    const float* __restrict__ x, bf16* __restrict__ o)
{
  size_t i = ((size_t)blockIdx.x*256 + threadIdx.x) * 8;
  float4 f0 = *(const float4*)(x + i);
  float4 f1 = *(const float4*)(x + i + 4);
  union { uint4 u; bf16 h[8]; } p;
  p.h[0] = __float2bfloat16(f0.x); p.h[1] = __float2bfloat16(f0.y);
  p.h[2] = __float2bfloat16(f0.z); p.h[3] = __float2bfloat16(f0.w);
  p.h[4] = __float2bfloat16(f1.x); p.h[5] = __float2bfloat16(f1.y);
  p.h[6] = __float2bfloat16(f1.z); p.h[7] = __float2bfloat16(f1.w);
  *(uint4*)(o + i) = p.u;
}

// ---------------------------------------------------------------------------
// Fused weight transpose: 5 weights f32 (RxC) -> bf16 (CxR), one dispatch.
// perm=1 (wff1): output rows interleave a/g columns.
// ---------------------------------------------------------------------------
struct TD { const float* src; bf16* dst; int R, C, base, perm; };
struct TDs5 { TD d[5]; };

__global__ __launch_bounds__(256) void wtrans_kernel(TDs5 a)
{
  const int blk = blockIdx.x;
  int di = 0;
  #pragma unroll
  for (int k = 1; k < 5; ++k) if (blk >= a.d[k].base) di = k;
  const TD d = a.d[di];
  const int local = blk - d.base;
  const int tilesX = d.C >> 5;
  const int by = local / tilesX, bx = local - by*tilesX;
  __shared__ float t[32][33];
  const int tx = threadIdx.x & 31, ty = threadIdx.x >> 5;
  const int c0 = bx*32, r0 = by*32;
  #pragma unroll
  for (int i = 0; i < 4; ++i)
    t[ty + i*8][tx] = d.src[(size_t)(r0 + ty + i*8)*d.C + c0 + tx];
  __syncthreads();
  const int half = d.C >> 1;
  #pragma unroll
  for (int i = 0; i < 4; ++i) {
    int c = c0 + ty + i*8;
    int rout = d.perm ? ((c < half) ? 2*c : 2*(c - half) + 1) : c;
    d.dst[(size_t)rout*d.R + r0 + tx] = __float2bfloat16(t[tx][ty + i*8]);
  }
}

// ---------------------------------------------------------------------------
extern "C" void kernel_launch(void* const* d_in, const int* in_sizes, int n_in,
                              void* d_out, int out_size, void* d_ws, size_t ws_size,
                              hipStream_t stream)
{
  const float* x_in       = (const float*)d_in[0];
  const float* attn_gamma = (const float*)d_in[1];
  const float* wq         = (const float*)d_in[2];
  const float* wkv        = (const float*)d_in[3];
  const float* q_scale    = (const float*)d_in[4];
  const float* k_scale    = (const float*)d_in[5];
  const float* wo         = (const float*)d_in[6];
  const float* ff_gamma   = (const float*)d_in[7];
  const float* ff_beta    = (const float*)d_in[8];
  const float* wff1       = (const float*)d_in[9];
  const float* wff2       = (const float*)d_in[10];
  float* outp = (float*)d_out;
  char* ws = (char*)d_ws;

  const size_t E = (size_t)ROWS * DIM;      // 3,145,728 elems
  float* xw32 = (float*)ws;                     // [0, 12.58M) f32 residual
  bf16*  xw16 = (bf16*)(ws + 12582912);         // bf16 shadow (kv input)
  bf16*  S_h  = (bf16*)(ws + 18874368);         // LN out / attn out
  char*  BIGb = ws + 25165824;                  // 37.75M scratch
  bf16*  WT   = (bf16*)(ws + 62914560);         // transposed weights
  bf16*  qbuf  = (bf16*)BIGb;                   // (dead: rope fused) E elems
  bf16*  qhb   = qbuf + 2*E;                    // E
  bf16*  khb   = qbuf + 3*E;                    // E
  bf16*  vtb   = qbuf + 4*E;                    // E
  bf16*  glbuf = (bf16*)BIGb;                   // ROWS*FFI (q..vt dead by then)
  float* wP    = (float*)BIGb;                  // wo partials 2E f32
  float* fP    = (float*)(BIGb + 16777216);     // ff2 partials 2E f32 (tail
                                                //   spills into dead wqT..woT,
                                                //   rebuilt next layer)
  bf16*  wqT   = WT;                            // [768][768]
  bf16*  wkvT  = WT + 589824;                   // [1536][768]
  bf16*  woT   = WT + 1769472;                  // [768][768]
  bf16*  wff1T = WT + 2359296;                  // [4096][768] (interleaved a/g)
  bf16*  wff2T = WT + 5505024;                  // [768][2048]

  // RoPE table: after WT if workspace allows (built once), else in BIGb
  // (clobbered by wP each layer -> rebuilt per layer).
  const size_t rtab_off = 77070336;             // WT end
  const bool tonce = ws_size >= rtab_off + 262144;
  float* rtab = tonce ? (float*)(ws + rtab_off) : (float*)BIGb;

  cast_kernel<<<1536, 256, 0, stream>>>(x_in, xw16);
  ln_kernel<<<ROWS, 256, 0, stream>>>(x_in, attn_gamma, nullptr, S_h);
  if (tonce) ropetab_kernel<<<128, 256, 0, stream>>>(rtab);

  for (int i = 0; i < NDEPTH; ++i) {
    const float* xsrc = (i == 0) ? x_in : xw32;

    TDs5 td;
    td.d[0] = { wq   + (size_t)i*589824,  wqT,   768,  768,    0, 0 };
    td.d[1] = { wkv  + (size_t)i*1179648, wkvT,  768, 1536,  576, 0 };
    td.d[2] = { wo   + (size_t)i*589824,  woT,   768,  768, 1728, 0 };
    td.d[3] = { wff1 + (size_t)i*3145728, wff1T, 768, 4096, 2304, 1 };
    td.d[4] = { wff2 + (size_t)i*1572864, wff2T, 2048, 768, 5376, 0 };
    wtrans_kernel<<<6912, 256, 0, stream>>>(td);
    if (!tonce) ropetab_kernel<<<128, 256, 0, stream>>>(rtab);

    // q/k: GEMM + fused rope+l2norm+scale -> qhb/khb ; v transposed -> vtb
    qkv_kernel<<<dim3(18,32), 256, 0, stream>>>(S_h, xw16, wqT, wkvT, rtab,
                                                q_scale + i*DH, k_scale + i*DH,
                                                qhb, khb, vtb);
    attn_kernel<<<dim3(16,48), 256, 0, stream>>>(qhb, khb, vtb,
                                                 q_scale + i*DH, k_scale + i*DH, S_h);
    // x = x + o @ wo (split-K=2) ; fused reduce + residual + ff-LN
    gemm_splitk_kernel<64,384,768><<<dim3(12,32,2), 256, 0, stream>>>(S_h, woT, wP, ROWS, DIM);
    redln_kernel<<<ROWS/4, 256, 0, stream>>>(wP, wP + E, xsrc, xw32, nullptr, nullptr,
                                             ff_gamma + i*DIM, ff_beta + i*DIM, S_h);
    // gl = a*gelu(g) fused in FF1 epilogue (256^2 2-phase kernel)
    gemm256_kernel<<<dim3(16,16), 512, 0, stream>>>(S_h, wff1T, glbuf, ROWS, 2*FFI);
    // x = x + gl @ wff2 (split-K=2) ; fused reduce + residual (+ next attn-LN)
    gemm_splitk_kernel<64,1024,2048><<<dim3(12,32,2), 256, 0, stream>>>(glbuf, wff2T, fP, ROWS, DIM);
    if (i < NDEPTH-1)
      redln_kernel<<<ROWS/4, 256, 0, stream>>>(fP, fP + E, xw32, xw32, xw16, nullptr,
                                               attn_gamma + (i+1)*DIM, nullptr, S_h);
    else
      redln_kernel<<<ROWS/4, 256, 0, stream>>>(fP, fP + E, xw32, nullptr, nullptr, outp,
                                               nullptr, nullptr, nullptr);
  }
}